// Round 1
// baseline (447.150 us; speedup 1.0000x reference)
//
#include <hip/hip_runtime.h>
#include <math.h>

// ---------------------------------------------------------------------------
// GCN 3-layer forward on MI355X.
// Decomposition per layer (D=64):
//   hs[i,:] = dinv[i] * (x[i,:] @ W)        (GEMM + scale epilogue)
//   out[i,:]= dinv[i] * (hs[i,:] + sum_{e: dst(e)=i} hs[src(e),:]) + b
//   optional LeakyReLU(0.01)
// dinv[i] = rsqrt(1 + indegree(i)).  CSR (grouped by dst) built per call.
// ---------------------------------------------------------------------------

constexpr int DTH = 256;         // default block size (multiple of 64)
constexpr int SCAN_CHUNK = 2048; // 256 threads * 8 items

__global__ void k_zero(int* __restrict__ p, int n) {
    int i = blockIdx.x * DTH + threadIdx.x;
    if (i < n) p[i] = 0;
}

__global__ void k_count(const int* __restrict__ dst, int E, int* __restrict__ cnt) {
    int i = blockIdx.x * DTH + threadIdx.x;
    if (i < E) atomicAdd(&cnt[dst[i]], 1);
}

// Block-local exclusive scan; writes local-exclusive values to row_ptr and
// per-block totals to bsum.
__global__ void k_scan1(const int* __restrict__ cnt, int n,
                        int* __restrict__ row_ptr, int* __restrict__ bsum) {
    __shared__ int sh[256];
    int tid = threadIdx.x;
    int base = blockIdx.x * SCAN_CHUNK + tid * 8;
    int v[8];
    int s = 0;
#pragma unroll
    for (int j = 0; j < 8; j++) {
        int idx = base + j;
        v[j] = (idx < n) ? cnt[idx] : 0;
        s += v[j];
    }
    sh[tid] = s;
    __syncthreads();
    for (int off = 1; off < 256; off <<= 1) {
        int add = (tid >= off) ? sh[tid - off] : 0;
        __syncthreads();
        sh[tid] += add;
        __syncthreads();
    }
    int excl = sh[tid] - s;  // exclusive prefix of this thread's 8 items
    int run = excl;
#pragma unroll
    for (int j = 0; j < 8; j++) {
        int idx = base + j;
        if (idx < n) row_ptr[idx] = run;
        run += v[j];
    }
    if (tid == 255) bsum[blockIdx.x] = sh[255];
}

// Exclusive scan of block sums (nb <= 256), single block.
__global__ void k_scan2(int* __restrict__ bsum, int nb) {
    __shared__ int sh[256];
    int tid = threadIdx.x;
    int v = (tid < nb) ? bsum[tid] : 0;
    sh[tid] = v;
    __syncthreads();
    for (int off = 1; off < 256; off <<= 1) {
        int add = (tid >= off) ? sh[tid - off] : 0;
        __syncthreads();
        sh[tid] += add;
        __syncthreads();
    }
    if (tid < nb) bsum[tid] = sh[tid] - v;  // exclusive
}

__global__ void k_scan3(int* __restrict__ row_ptr, int n,
                        const int* __restrict__ bsum, int E) {
    int i = blockIdx.x * DTH + threadIdx.x;
    if (i < n) row_ptr[i] += bsum[i / SCAN_CHUNK];
    if (i == 0) row_ptr[n] = E;
}

__global__ void k_fill(const int* __restrict__ src, const int* __restrict__ dst, int E,
                       const int* __restrict__ row_ptr, int* __restrict__ cursor,
                       int* __restrict__ col) {
    int i = blockIdx.x * DTH + threadIdx.x;
    if (i < E) {
        int d = dst[i];
        int pos = row_ptr[d] + atomicAdd(&cursor[d], 1);
        col[pos] = src[i];
    }
}

// hs[row,:] = dinv[row] * (X[row,:] @ W), 16 rows per block of 256 threads.
__global__ void k_gemm_scale(const float* __restrict__ X, const float* __restrict__ W,
                             const int* __restrict__ row_ptr, int n,
                             float* __restrict__ HS) {
    __shared__ float Ws[64][64];      // 16 KB
    __shared__ float Xs[16][68];      // padded: bank-conflict-free broadcast reads
    int tid = threadIdx.x;

    // stage W (4096 floats = 1024 float4; 256 threads x 4)
    {
        const float4* W4 = (const float4*)W;
        float4* Ws4 = (float4*)&Ws[0][0];
#pragma unroll
        for (int j = 0; j < 4; j++) Ws4[tid + 256 * j] = W4[tid + 256 * j];
    }
    int row0 = blockIdx.x * 16;
    int r = tid >> 4;
    int c4 = (tid & 15) * 4;
    // stage X tile
    {
        int grow = row0 + r;
        float4 xv = make_float4(0.f, 0.f, 0.f, 0.f);
        if (grow < n) xv = *(const float4*)&X[(size_t)grow * 64 + c4];
        *(float4*)&Xs[r][c4] = xv;
    }
    __syncthreads();

    float4 acc = make_float4(0.f, 0.f, 0.f, 0.f);
#pragma unroll
    for (int k = 0; k < 64; k++) {
        float xv = Xs[r][k];
        float4 wv = *(const float4*)&Ws[k][c4];
        acc.x += xv * wv.x;
        acc.y += xv * wv.y;
        acc.z += xv * wv.z;
        acc.w += xv * wv.w;
    }
    int grow = row0 + r;
    if (grow < n) {
        float deg = 1.0f + (float)(row_ptr[grow + 1] - row_ptr[grow]);
        float dinv = rsqrtf(deg);
        acc.x *= dinv; acc.y *= dinv; acc.z *= dinv; acc.w *= dinv;
        *(float4*)&HS[(size_t)grow * 64 + c4] = acc;
    }
}

// One wave per node; lane = feature.  out = dinv*(hs_self + sum hs[src]) + b.
template <bool RELU>
__global__ void k_agg(const float* __restrict__ HS, const int* __restrict__ row_ptr,
                      const int* __restrict__ col, const float* __restrict__ bias,
                      int n, float* __restrict__ out) {
    int wave = (int)((blockIdx.x * (unsigned)blockDim.x + threadIdx.x) >> 6);
    int lane = threadIdx.x & 63;
    if (wave >= n) return;

    int r0 = row_ptr[wave];
    int r1 = row_ptr[wave + 1];

    float a0 = HS[(size_t)wave * 64 + lane];
    float a1 = 0.f, a2 = 0.f, a3 = 0.f;

    int e = r0;
    for (; e + 4 <= r1; e += 4) {
        int s0 = col[e + 0];
        int s1 = col[e + 1];
        int s2 = col[e + 2];
        int s3 = col[e + 3];
        a0 += HS[(size_t)s0 * 64 + lane];
        a1 += HS[(size_t)s1 * 64 + lane];
        a2 += HS[(size_t)s2 * 64 + lane];
        a3 += HS[(size_t)s3 * 64 + lane];
    }
    for (; e < r1; e++) a0 += HS[(size_t)col[e] * 64 + lane];

    float acc = (a0 + a1) + (a2 + a3);
    float deg = 1.0f + (float)(r1 - r0);
    float dinv = rsqrtf(deg);
    float v = dinv * acc + bias[lane];
    if (RELU) v = (v >= 0.f) ? v : 0.01f * v;
    out[(size_t)wave * 64 + lane] = v;
}

static inline size_t align256(size_t x) { return (x + 255) & ~(size_t)255; }

extern "C" void kernel_launch(void* const* d_in, const int* in_sizes, int n_in,
                              void* d_out, int out_size, void* d_ws, size_t ws_size,
                              hipStream_t stream) {
    const float* x  = (const float*)d_in[0];
    const float* W1 = (const float*)d_in[1];
    const float* b1 = (const float*)d_in[2];
    const float* W2 = (const float*)d_in[3];
    const float* b2 = (const float*)d_in[4];
    const float* W3 = (const float*)d_in[5];
    const float* b3 = (const float*)d_in[6];
    const int* edge = (const int*)d_in[7];

    int n = in_sizes[0] / 64;
    int E = in_sizes[7] / 2;
    const int* srcp = edge;
    const int* dstp = edge + E;

    char* ws = (char*)d_ws;
    int* row_ptr = (int*)ws;           ws += align256((size_t)(n + 1) * 4);
    int* cnt     = (int*)ws;           ws += align256((size_t)n * 4);      // reused as cursor
    int* bsum    = (int*)ws;           ws += align256(256 * 4);
    int* col     = (int*)ws;           ws += align256((size_t)E * 4);
    float* hs    = (float*)ws;         ws += align256((size_t)n * 64 * 4);
    float* buf   = (float*)ws;         ws += align256((size_t)n * 64 * 4);
    float* out   = (float*)d_out;

    int nb = (n + SCAN_CHUNK - 1) / SCAN_CHUNK;

    // ---- CSR build (per call; deterministic up to atomic ordering) ----
    k_zero<<<(n + DTH - 1) / DTH, DTH, 0, stream>>>(cnt, n);
    k_count<<<(E + DTH - 1) / DTH, DTH, 0, stream>>>(dstp, E, cnt);
    k_scan1<<<nb, 256, 0, stream>>>(cnt, n, row_ptr, bsum);
    k_scan2<<<1, 256, 0, stream>>>(bsum, nb);
    k_scan3<<<(n + DTH - 1) / DTH, DTH, 0, stream>>>(row_ptr, n, bsum, E);
    k_zero<<<(n + DTH - 1) / DTH, DTH, 0, stream>>>(cnt, n);  // cursor
    k_fill<<<(E + DTH - 1) / DTH, DTH, 0, stream>>>(srcp, dstp, E, row_ptr, cnt, col);

    int gemm_blocks = (n + 15) / 16;
    int agg_blocks  = (n + 3) / 4;  // 4 waves (nodes) per 256-thread block

    // ---- layer 1: conv -> LeakyReLU ----
    k_gemm_scale<<<gemm_blocks, 256, 0, stream>>>(x, W1, row_ptr, n, hs);
    k_agg<true><<<agg_blocks, 256, 0, stream>>>(hs, row_ptr, col, b1, n, out);
    // ---- layer 2: conv (no activation) ----
    k_gemm_scale<<<gemm_blocks, 256, 0, stream>>>(out, W2, row_ptr, n, hs);
    k_agg<false><<<agg_blocks, 256, 0, stream>>>(hs, row_ptr, col, b2, n, buf);
    // ---- layer 3: conv -> LeakyReLU ----
    k_gemm_scale<<<gemm_blocks, 256, 0, stream>>>(buf, W3, row_ptr, n, hs);
    k_agg<true><<<agg_blocks, 256, 0, stream>>>(hs, row_ptr, col, b3, n, out);
}

// Round 2
// 410.911 us; speedup vs baseline: 1.0882x; 1.0882x over previous
//
#include <hip/hip_runtime.h>
#include <math.h>

// ---------------------------------------------------------------------------
// GCN 3-layer forward on MI355X.
// Per layer (D=64):
//   hs[i,:] = dinv[i] * (x[i,:] @ W)
//   out[i,:]= dinv[i] * (hs[i,:] + sum_{e: dst(e)=i} hs[src(e),:]) + b
//   optional LeakyReLU(0.01);   dinv[i] = rsqrt(1 + indeg(i))
//
// CSR build strategy (round 2): linked-list chaining (one atomicExch per
// edge, coalesced link writes) + node-parallel chain walks for count and
// for contiguous col writeout. Avoids the 107MB partial-line scatter-write
// traffic the atomic-cursor fill produced.
// ---------------------------------------------------------------------------

constexpr int DTH = 256;
constexpr int SCAN_CHUNK = 2048; // 256 threads * 8 items

__global__ void k_fill_i32(int* __restrict__ p, int n, int val) {
    int i = blockIdx.x * DTH + threadIdx.x;
    if (i < n) p[i] = val;
}

// old = atomicExch(head[dst], e); link[e] = {old, src[e]}  (coalesced write)
__global__ void k_link(const int* __restrict__ src, const int* __restrict__ dst, int E,
                       int* __restrict__ head, int2* __restrict__ link) {
    int i = blockIdx.x * DTH + threadIdx.x;
    if (i < E) {
        int d = dst[i];
        int old = atomicExch(&head[d], i);
        link[i] = make_int2(old, src[i]);
    }
}

// thread-per-node: chain length -> cnt[i]
__global__ void k_chain_count(const int* __restrict__ head, const int2* __restrict__ link,
                              int n, int* __restrict__ cnt) {
    int i = blockIdx.x * DTH + threadIdx.x;
    if (i < n) {
        int c = 0;
        int e = head[i];
        while (e >= 0) { c++; e = link[e].x; }
        cnt[i] = c;
    }
}

// thread-per-node: write this node's col segment contiguously
__global__ void k_chain_fill(const int* __restrict__ head, const int2* __restrict__ link,
                             const int* __restrict__ row_ptr, int n, int* __restrict__ col) {
    int i = blockIdx.x * DTH + threadIdx.x;
    if (i < n) {
        int p = row_ptr[i];
        int e = head[i];
        while (e >= 0) {
            int2 L = link[e];
            col[p++] = L.y;
            e = L.x;
        }
    }
}

// Block-local exclusive scan; local-exclusive to row_ptr, block totals to bsum.
__global__ void k_scan1(const int* __restrict__ cnt, int n,
                        int* __restrict__ row_ptr, int* __restrict__ bsum) {
    __shared__ int sh[256];
    int tid = threadIdx.x;
    int base = blockIdx.x * SCAN_CHUNK + tid * 8;
    int v[8];
    int s = 0;
#pragma unroll
    for (int j = 0; j < 8; j++) {
        int idx = base + j;
        v[j] = (idx < n) ? cnt[idx] : 0;
        s += v[j];
    }
    sh[tid] = s;
    __syncthreads();
    for (int off = 1; off < 256; off <<= 1) {
        int add = (tid >= off) ? sh[tid - off] : 0;
        __syncthreads();
        sh[tid] += add;
        __syncthreads();
    }
    int run = sh[tid] - s;
#pragma unroll
    for (int j = 0; j < 8; j++) {
        int idx = base + j;
        if (idx < n) row_ptr[idx] = run;
        run += v[j];
    }
    if (tid == 255) bsum[blockIdx.x] = sh[255];
}

__global__ void k_scan2(int* __restrict__ bsum, int nb) {
    __shared__ int sh[256];
    int tid = threadIdx.x;
    int v = (tid < nb) ? bsum[tid] : 0;
    sh[tid] = v;
    __syncthreads();
    for (int off = 1; off < 256; off <<= 1) {
        int add = (tid >= off) ? sh[tid - off] : 0;
        __syncthreads();
        sh[tid] += add;
        __syncthreads();
    }
    if (tid < nb) bsum[tid] = sh[tid] - v;
}

__global__ void k_scan3(int* __restrict__ row_ptr, int n,
                        const int* __restrict__ bsum, int E) {
    int i = blockIdx.x * DTH + threadIdx.x;
    if (i < n) row_ptr[i] += bsum[i / SCAN_CHUNK];
    if (i == 0) row_ptr[n] = E;
}

// hs[row,:] = dinv[row] * (X[row,:] @ W), 16 rows per 256-thread block.
__global__ void k_gemm_scale(const float* __restrict__ X, const float* __restrict__ W,
                             const int* __restrict__ row_ptr, int n,
                             float* __restrict__ HS) {
    __shared__ float Ws[64][64];
    __shared__ float Xs[16][68];
    int tid = threadIdx.x;
    {
        const float4* W4 = (const float4*)W;
        float4* Ws4 = (float4*)&Ws[0][0];
#pragma unroll
        for (int j = 0; j < 4; j++) Ws4[tid + 256 * j] = W4[tid + 256 * j];
    }
    int row0 = blockIdx.x * 16;
    int r = tid >> 4;
    int c4 = (tid & 15) * 4;
    {
        int grow = row0 + r;
        float4 xv = make_float4(0.f, 0.f, 0.f, 0.f);
        if (grow < n) xv = *(const float4*)&X[(size_t)grow * 64 + c4];
        *(float4*)&Xs[r][c4] = xv;
    }
    __syncthreads();

    float4 acc = make_float4(0.f, 0.f, 0.f, 0.f);
#pragma unroll
    for (int k = 0; k < 64; k++) {
        float xv = Xs[r][k];
        float4 wv = *(const float4*)&Ws[k][c4];
        acc.x += xv * wv.x;
        acc.y += xv * wv.y;
        acc.z += xv * wv.z;
        acc.w += xv * wv.w;
    }
    int grow = row0 + r;
    if (grow < n) {
        float deg = 1.0f + (float)(row_ptr[grow + 1] - row_ptr[grow]);
        float dinv = rsqrtf(deg);
        acc.x *= dinv; acc.y *= dinv; acc.z *= dinv; acc.w *= dinv;
        *(float4*)&HS[(size_t)grow * 64 + c4] = acc;
    }
}

// One wave per node; lane = feature.
template <bool RELU>
__global__ void k_agg(const float* __restrict__ HS, const int* __restrict__ row_ptr,
                      const int* __restrict__ col, const float* __restrict__ bias,
                      int n, float* __restrict__ out) {
    int wave = (int)((blockIdx.x * (unsigned)blockDim.x + threadIdx.x) >> 6);
    int lane = threadIdx.x & 63;
    if (wave >= n) return;

    int r0 = row_ptr[wave];
    int r1 = row_ptr[wave + 1];

    float a0 = HS[(size_t)wave * 64 + lane];
    float a1 = 0.f, a2 = 0.f, a3 = 0.f;

    int e = r0;
    for (; e + 4 <= r1; e += 4) {
        int s0 = col[e + 0];
        int s1 = col[e + 1];
        int s2 = col[e + 2];
        int s3 = col[e + 3];
        a0 += HS[(size_t)s0 * 64 + lane];
        a1 += HS[(size_t)s1 * 64 + lane];
        a2 += HS[(size_t)s2 * 64 + lane];
        a3 += HS[(size_t)s3 * 64 + lane];
    }
    for (; e < r1; e++) a0 += HS[(size_t)col[e] * 64 + lane];

    float acc = (a0 + a1) + (a2 + a3);
    float deg = 1.0f + (float)(r1 - r0);
    float dinv = rsqrtf(deg);
    float v = dinv * acc + bias[lane];
    if (RELU) v = (v >= 0.f) ? v : 0.01f * v;
    out[(size_t)wave * 64 + lane] = v;
}

static inline size_t align256(size_t x) { return (x + 255) & ~(size_t)255; }

extern "C" void kernel_launch(void* const* d_in, const int* in_sizes, int n_in,
                              void* d_out, int out_size, void* d_ws, size_t ws_size,
                              hipStream_t stream) {
    const float* x  = (const float*)d_in[0];
    const float* W1 = (const float*)d_in[1];
    const float* b1 = (const float*)d_in[2];
    const float* W2 = (const float*)d_in[3];
    const float* b2 = (const float*)d_in[4];
    const float* W3 = (const float*)d_in[5];
    const float* b3 = (const float*)d_in[6];
    const int* edge = (const int*)d_in[7];

    int n = in_sizes[0] / 64;
    int E = in_sizes[7] / 2;
    const int* srcp = edge;
    const int* dstp = edge + E;

    char* ws = (char*)d_ws;
    int* row_ptr = (int*)ws;   ws += align256((size_t)(n + 1) * 4);
    int* cnt     = (int*)ws;   ws += align256((size_t)n * 4);
    int* head    = (int*)ws;   ws += align256((size_t)n * 4);
    int* bsum    = (int*)ws;   ws += align256(256 * 4);
    int* col     = (int*)ws;   ws += align256((size_t)E * 4);
    float* hs    = (float*)ws; ws += align256((size_t)n * 64 * 4);
    float* buf   = (float*)ws; ws += align256((size_t)n * 64 * 4);
    float* out   = (float*)d_out;
    // link aliases hs: link is dead before the first k_gemm_scale writes hs.
    int2* link   = (int2*)hs;

    int nb = (n + SCAN_CHUNK - 1) / SCAN_CHUNK;
    int nblk = (n + DTH - 1) / DTH;
    int eblk = (E + DTH - 1) / DTH;

    // ---- CSR build via linked-list chaining ----
    k_fill_i32<<<nblk, DTH, 0, stream>>>(head, n, -1);
    k_link<<<eblk, DTH, 0, stream>>>(srcp, dstp, E, head, link);
    k_chain_count<<<nblk, DTH, 0, stream>>>(head, link, n, cnt);
    k_scan1<<<nb, 256, 0, stream>>>(cnt, n, row_ptr, bsum);
    k_scan2<<<1, 256, 0, stream>>>(bsum, nb);
    k_scan3<<<nblk, DTH, 0, stream>>>(row_ptr, n, bsum, E);
    k_chain_fill<<<nblk, DTH, 0, stream>>>(head, link, row_ptr, n, col);

    int gemm_blocks = (n + 15) / 16;
    int agg_blocks  = (n + 3) / 4;

    // ---- layer 1: conv -> LeakyReLU ----
    k_gemm_scale<<<gemm_blocks, 256, 0, stream>>>(x, W1, row_ptr, n, hs);
    k_agg<true><<<agg_blocks, 256, 0, stream>>>(hs, row_ptr, col, b1, n, out);
    // ---- layer 2: conv ----
    k_gemm_scale<<<gemm_blocks, 256, 0, stream>>>(out, W2, row_ptr, n, hs);
    k_agg<false><<<agg_blocks, 256, 0, stream>>>(hs, row_ptr, col, b2, n, buf);
    // ---- layer 3: conv -> LeakyReLU ----
    k_gemm_scale<<<gemm_blocks, 256, 0, stream>>>(buf, W3, row_ptr, n, hs);
    k_agg<true><<<agg_blocks, 256, 0, stream>>>(hs, row_ptr, col, b3, n, out);
}

// Round 3
// 388.425 us; speedup vs baseline: 1.1512x; 1.0579x over previous
//
#include <hip/hip_runtime.h>
#include <hip/hip_fp16.h>
#include <math.h>

// ---------------------------------------------------------------------------
// GCN 3-layer forward on MI355X.
// Per layer (D=64):
//   hs[i,:] = fp16( dinv[i] * (x[i,:] @ W) )      (GEMM + scale epilogue)
//   out[i,:]= dinv[i] * (hs[i,:] + sum_{e: dst(e)=i} hs[src(e),:]) + b
//   optional LeakyReLU(0.01);   dinv[i] = rsqrt(1 + indeg(i))
//
// Round-3 changes:
//  - hs stored fp16: halves the random-gather line traffic in k_agg
//    (128B/edge instead of 256B/edge).  Intermediates stay fp32.
//  - head table padded to one node per 64B line: kills the 256-atomics-per-
//    line false sharing that made k_link TCC-serialization-bound.
// ---------------------------------------------------------------------------

constexpr int DTH = 256;
constexpr int SCAN_CHUNK = 2048; // 256 threads * 8 items
constexpr int HPAD = 16;         // head stride in ints (64B line per node)

__global__ void k_fill_i32(int* __restrict__ p, int n, int val) {
    int i = blockIdx.x * DTH + threadIdx.x;
    if (i < n) p[i] = val;
}

// old = atomicExch(head[dst*HPAD], e); link[e] = {old, src[e]} (coalesced)
__global__ void k_link(const int* __restrict__ src, const int* __restrict__ dst, int E,
                       int* __restrict__ head, int2* __restrict__ link) {
    int i = blockIdx.x * DTH + threadIdx.x;
    if (i < E) {
        int d = dst[i];
        int old = atomicExch(&head[(size_t)d * HPAD], i);
        link[i] = make_int2(old, src[i]);
    }
}

// thread-per-node: chain length -> cnt[i]
__global__ void k_chain_count(const int* __restrict__ head, const int2* __restrict__ link,
                              int n, int* __restrict__ cnt) {
    int i = blockIdx.x * DTH + threadIdx.x;
    if (i < n) {
        int c = 0;
        int e = head[(size_t)i * HPAD];
        while (e >= 0) { c++; e = link[e].x; }
        cnt[i] = c;
    }
}

// thread-per-node: write this node's col segment contiguously
__global__ void k_chain_fill(const int* __restrict__ head, const int2* __restrict__ link,
                             const int* __restrict__ row_ptr, int n, int* __restrict__ col) {
    int i = blockIdx.x * DTH + threadIdx.x;
    if (i < n) {
        int p = row_ptr[i];
        int e = head[(size_t)i * HPAD];
        while (e >= 0) {
            int2 L = link[e];
            col[p++] = L.y;
            e = L.x;
        }
    }
}

// Block-local exclusive scan; local-exclusive to row_ptr, block totals to bsum.
__global__ void k_scan1(const int* __restrict__ cnt, int n,
                        int* __restrict__ row_ptr, int* __restrict__ bsum) {
    __shared__ int sh[256];
    int tid = threadIdx.x;
    int base = blockIdx.x * SCAN_CHUNK + tid * 8;
    int v[8];
    int s = 0;
#pragma unroll
    for (int j = 0; j < 8; j++) {
        int idx = base + j;
        v[j] = (idx < n) ? cnt[idx] : 0;
        s += v[j];
    }
    sh[tid] = s;
    __syncthreads();
    for (int off = 1; off < 256; off <<= 1) {
        int add = (tid >= off) ? sh[tid - off] : 0;
        __syncthreads();
        sh[tid] += add;
        __syncthreads();
    }
    int run = sh[tid] - s;
#pragma unroll
    for (int j = 0; j < 8; j++) {
        int idx = base + j;
        if (idx < n) row_ptr[idx] = run;
        run += v[j];
    }
    if (tid == 255) bsum[blockIdx.x] = sh[255];
}

__global__ void k_scan2(int* __restrict__ bsum, int nb) {
    __shared__ int sh[256];
    int tid = threadIdx.x;
    int v = (tid < nb) ? bsum[tid] : 0;
    sh[tid] = v;
    __syncthreads();
    for (int off = 1; off < 256; off <<= 1) {
        int add = (tid >= off) ? sh[tid - off] : 0;
        __syncthreads();
        sh[tid] += add;
        __syncthreads();
    }
    if (tid < nb) bsum[tid] = sh[tid] - v;
}

__global__ void k_scan3(int* __restrict__ row_ptr, int n,
                        const int* __restrict__ bsum, int E) {
    int i = blockIdx.x * DTH + threadIdx.x;
    if (i < n) row_ptr[i] += bsum[i / SCAN_CHUNK];
    if (i == 0) row_ptr[n] = E;
}

// HS[row,:] = fp16(dinv[row] * (X[row,:] @ W)), 16 rows per 256-thread block.
__global__ void k_gemm_scale(const float* __restrict__ X, const float* __restrict__ W,
                             const int* __restrict__ row_ptr, int n,
                             __half* __restrict__ HS) {
    __shared__ float Ws[64][64];
    __shared__ float Xs[16][68];
    int tid = threadIdx.x;
    {
        const float4* W4 = (const float4*)W;
        float4* Ws4 = (float4*)&Ws[0][0];
#pragma unroll
        for (int j = 0; j < 4; j++) Ws4[tid + 256 * j] = W4[tid + 256 * j];
    }
    int row0 = blockIdx.x * 16;
    int r = tid >> 4;
    int c4 = (tid & 15) * 4;
    {
        int grow = row0 + r;
        float4 xv = make_float4(0.f, 0.f, 0.f, 0.f);
        if (grow < n) xv = *(const float4*)&X[(size_t)grow * 64 + c4];
        *(float4*)&Xs[r][c4] = xv;
    }
    __syncthreads();

    float4 acc = make_float4(0.f, 0.f, 0.f, 0.f);
#pragma unroll
    for (int k = 0; k < 64; k++) {
        float xv = Xs[r][k];
        float4 wv = *(const float4*)&Ws[k][c4];
        acc.x += xv * wv.x;
        acc.y += xv * wv.y;
        acc.z += xv * wv.z;
        acc.w += xv * wv.w;
    }
    int grow = row0 + r;
    if (grow < n) {
        float deg = 1.0f + (float)(row_ptr[grow + 1] - row_ptr[grow]);
        float dinv = rsqrtf(deg);
        __half2 h0 = __floats2half2_rn(acc.x * dinv, acc.y * dinv);
        __half2 h1 = __floats2half2_rn(acc.z * dinv, acc.w * dinv);
        uint2 pack;
        pack.x = *(const unsigned int*)&h0;
        pack.y = *(const unsigned int*)&h1;
        *(uint2*)&HS[(size_t)grow * 64 + c4] = pack;
    }
}

// One wave per node; lane = feature.  fp16 gathers, fp32 accumulate.
template <bool RELU>
__global__ void k_agg(const __half* __restrict__ HS, const int* __restrict__ row_ptr,
                      const int* __restrict__ col, const float* __restrict__ bias,
                      int n, float* __restrict__ out) {
    int wave = (int)((blockIdx.x * (unsigned)blockDim.x + threadIdx.x) >> 6);
    int lane = threadIdx.x & 63;
    if (wave >= n) return;

    int r0 = row_ptr[wave];
    int r1 = row_ptr[wave + 1];

    float a0 = __half2float(HS[(size_t)wave * 64 + lane]);
    float a1 = 0.f, a2 = 0.f, a3 = 0.f;

    int e = r0;
    for (; e + 4 <= r1; e += 4) {
        int s0 = col[e + 0];
        int s1 = col[e + 1];
        int s2 = col[e + 2];
        int s3 = col[e + 3];
        a0 += __half2float(HS[(size_t)s0 * 64 + lane]);
        a1 += __half2float(HS[(size_t)s1 * 64 + lane]);
        a2 += __half2float(HS[(size_t)s2 * 64 + lane]);
        a3 += __half2float(HS[(size_t)s3 * 64 + lane]);
    }
    for (; e < r1; e++) a0 += __half2float(HS[(size_t)col[e] * 64 + lane]);

    float acc = (a0 + a1) + (a2 + a3);
    float deg = 1.0f + (float)(r1 - r0);
    float dinv = rsqrtf(deg);
    float v = dinv * acc + bias[lane];
    if (RELU) v = (v >= 0.f) ? v : 0.01f * v;
    out[(size_t)wave * 64 + lane] = v;
}

static inline size_t align256(size_t x) { return (x + 255) & ~(size_t)255; }

extern "C" void kernel_launch(void* const* d_in, const int* in_sizes, int n_in,
                              void* d_out, int out_size, void* d_ws, size_t ws_size,
                              hipStream_t stream) {
    const float* x  = (const float*)d_in[0];
    const float* W1 = (const float*)d_in[1];
    const float* b1 = (const float*)d_in[2];
    const float* W2 = (const float*)d_in[3];
    const float* b2 = (const float*)d_in[4];
    const float* W3 = (const float*)d_in[5];
    const float* b3 = (const float*)d_in[6];
    const int* edge = (const int*)d_in[7];

    int n = in_sizes[0] / 64;
    int E = in_sizes[7] / 2;
    const int* srcp = edge;
    const int* dstp = edge + E;

    char* ws = (char*)d_ws;
    int* row_ptr  = (int*)ws;    ws += align256((size_t)(n + 1) * 4);
    int* cnt      = (int*)ws;    ws += align256((size_t)n * 4);
    int* headp    = (int*)ws;    ws += align256((size_t)n * HPAD * 4);  // 64B/node
    int* bsum     = (int*)ws;    ws += align256(256 * 4);
    int* col      = (int*)ws;    ws += align256((size_t)E * 4);
    __half* hs    = (__half*)ws; ws += align256((size_t)n * 64 * 2);
    float* buf    = (float*)ws;  ws += align256((size_t)n * 64 * 4);
    float* out    = (float*)d_out;
    // link aliases buf: link is dead before layer-2's k_agg writes buf.
    int2* link    = (int2*)buf;

    int nb = (n + SCAN_CHUNK - 1) / SCAN_CHUNK;
    int nblk = (n + DTH - 1) / DTH;
    int eblk = (E + DTH - 1) / DTH;
    int hblk = ((n * HPAD) + DTH - 1) / DTH;

    // ---- CSR build via linked-list chaining (padded head) ----
    k_fill_i32<<<hblk, DTH, 0, stream>>>(headp, n * HPAD, -1);
    k_link<<<eblk, DTH, 0, stream>>>(srcp, dstp, E, headp, link);
    k_chain_count<<<nblk, DTH, 0, stream>>>(headp, link, n, cnt);
    k_scan1<<<nb, 256, 0, stream>>>(cnt, n, row_ptr, bsum);
    k_scan2<<<1, 256, 0, stream>>>(bsum, nb);
    k_scan3<<<nblk, DTH, 0, stream>>>(row_ptr, n, bsum, E);
    k_chain_fill<<<nblk, DTH, 0, stream>>>(headp, link, row_ptr, n, col);

    int gemm_blocks = (n + 15) / 16;
    int agg_blocks  = (n + 3) / 4;

    // ---- layer 1: conv -> LeakyReLU ----
    k_gemm_scale<<<gemm_blocks, 256, 0, stream>>>(x, W1, row_ptr, n, hs);
    k_agg<true><<<agg_blocks, 256, 0, stream>>>(hs, row_ptr, col, b1, n, out);
    // ---- layer 2: conv ----
    k_gemm_scale<<<gemm_blocks, 256, 0, stream>>>(out, W2, row_ptr, n, hs);
    k_agg<false><<<agg_blocks, 256, 0, stream>>>(hs, row_ptr, col, b2, n, buf);
    // ---- layer 3: conv -> LeakyReLU ----
    k_gemm_scale<<<gemm_blocks, 256, 0, stream>>>(buf, W3, row_ptr, n, hs);
    k_agg<true><<<agg_blocks, 256, 0, stream>>>(hs, row_ptr, col, b3, n, out);
}

// Round 4
// 300.110 us; speedup vs baseline: 1.4900x; 1.2943x over previous
//
#include <hip/hip_runtime.h>
#include <hip/hip_fp16.h>
#include <math.h>

// ---------------------------------------------------------------------------
// GCN 3-layer forward on MI355X.
// Per layer (D=64):
//   hs[i,:] = fp16( dinv[i] * (x[i,:] @ W) )
//   out[i,:]= dinv[i] * (hs[i,:] + sum_{e: dst(e)=i} hs[src(e),:]) + b
//   optional LeakyReLU(0.01);   dinv[i] = rsqrt(1 + indeg(i))
//
// Round-4: CSR build via atomic-free two-level bucket sort.
//   k_link's atomicExch wrote ~32B/atomic through to memory (62.5MB) and the
//   chain walks were random 64B-line pointer chases (~100MB each).  Replaced
//   with: per-block histogram -> deterministic scans -> bucket scatter
//   (packed 4B records) -> per-bucket LDS counting sort emitting row_ptr+col.
//   Only LDS atomics remain.
// ---------------------------------------------------------------------------

constexpr int DTH = 256;
constexpr int SHIFT = 8;          // bucket = dst >> 8  (256 nodes per bucket)
constexpr int CHUNK = 4096;       // edges per phase-1/scatter block

// ---- phase 1: per-block bucket histogram (block-major layout Bh[j*NB+b]) ----
__global__ void k_hist(const int* __restrict__ dst, int E, int NB,
                       int* __restrict__ Bh) {
    __shared__ int h[512];
    int tid = threadIdx.x;
    for (int i = tid; i < NB; i += 256) h[i] = 0;
    __syncthreads();
    int s = blockIdx.x * CHUNK;
    int e = min(s + CHUNK, E);
    for (int i = s + tid; i < e; i += 256) atomicAdd(&h[dst[i] >> SHIFT], 1);
    __syncthreads();
    for (int i = tid; i < NB; i += 256) Bh[(size_t)blockIdx.x * NB + i] = h[i];
}

// ---- phase 1b: per-bucket exclusive scan down the block axis ----
__global__ void k_bucket_scan(int* __restrict__ Bh, int B1, int NB,
                              int* __restrict__ total) {
    __shared__ int sh[256];
    int b = blockIdx.x;
    int tid = threadIdx.x;
    int carry = 0;
    for (int j0 = 0; j0 < B1; j0 += 256) {
        int j = j0 + tid;
        int v = (j < B1) ? Bh[(size_t)j * NB + b] : 0;
        sh[tid] = v;
        __syncthreads();
        for (int off = 1; off < 256; off <<= 1) {
            int add = (tid >= off) ? sh[tid - off] : 0;
            __syncthreads();
            sh[tid] += add;
            __syncthreads();
        }
        int excl = sh[tid] - v + carry;
        if (j < B1) Bh[(size_t)j * NB + b] = excl;
        int tot = sh[255];
        __syncthreads();
        carry += tot;
    }
    if (tid == 0) total[b] = carry;
}

// ---- phase 1c: exclusive scan of bucket totals (NB <= 512), single block ----
__global__ void k_base_scan(const int* __restrict__ total, int NB, int E,
                            int* __restrict__ base) {
    __shared__ int sh[512];
    int tid = threadIdx.x;
    int v = (tid < NB) ? total[tid] : 0;
    sh[tid] = v;
    __syncthreads();
    for (int off = 1; off < 512; off <<= 1) {
        int add = (tid >= off) ? sh[tid - off] : 0;
        __syncthreads();
        sh[tid] += add;
        __syncthreads();
    }
    if (tid < NB) base[tid] = sh[tid] - v;
    if (tid == 0) base[NB] = E;
}

// ---- phase 2: scatter packed records into bucket-contiguous ebuf ----
// record = (dst & 255) << 24 | src      (src < 2^17)
__global__ void k_scatter(const int* __restrict__ src, const int* __restrict__ dst,
                          int E, int NB, const int* __restrict__ Bh,
                          const int* __restrict__ base, unsigned* __restrict__ ebuf) {
    __shared__ int cur[512];
    int tid = threadIdx.x;
    for (int i = tid; i < NB; i += 256)
        cur[i] = base[i] + Bh[(size_t)blockIdx.x * NB + i];
    __syncthreads();
    int s = blockIdx.x * CHUNK;
    int e = min(s + CHUNK, E);
    for (int i = s + tid; i < e; i += 256) {
        int d = dst[i];
        int b = d >> SHIFT;
        int pos = atomicAdd(&cur[b], 1);
        ebuf[pos] = ((unsigned)(d & 255) << 24) | (unsigned)src[i];
    }
}

// ---- phase 3: per-bucket counting sort -> row_ptr + col ----
__global__ void k_bucket_sort(const unsigned* __restrict__ ebuf,
                              const int* __restrict__ base, int n, int E,
                              int* __restrict__ row_ptr, int* __restrict__ col) {
    __shared__ int cnt[256];
    __shared__ int sh[256];
    __shared__ int cur[256];
    int b = blockIdx.x;
    int tid = threadIdx.x;
    int s = base[b];
    int e = base[b + 1];
    cnt[tid] = 0;
    __syncthreads();
    for (int i = s + tid; i < e; i += 256) atomicAdd(&cnt[ebuf[i] >> 24], 1);
    __syncthreads();
    int c = cnt[tid];
    sh[tid] = c;
    __syncthreads();
    for (int off = 1; off < 256; off <<= 1) {
        int add = (tid >= off) ? sh[tid - off] : 0;
        __syncthreads();
        sh[tid] += add;
        __syncthreads();
    }
    int excl = sh[tid] - c;
    int node = (b << SHIFT) | tid;
    if (node < n) row_ptr[node] = s + excl;
    cur[tid] = s + excl;
    __syncthreads();
    for (int i = s + tid; i < e; i += 256) {
        unsigned v = ebuf[i];
        int pos = atomicAdd(&cur[v >> 24], 1);
        col[pos] = (int)(v & 0x00FFFFFFu);
    }
    if (b == 0 && tid == 0) row_ptr[n] = E;
}

// ---- HS[row,:] = fp16(dinv[row] * (X[row,:] @ W)), 16 rows / 256 threads ----
__global__ void k_gemm_scale(const float* __restrict__ X, const float* __restrict__ W,
                             const int* __restrict__ row_ptr, int n,
                             __half* __restrict__ HS) {
    __shared__ float Ws[64][64];
    __shared__ float Xs[16][68];
    int tid = threadIdx.x;
    {
        const float4* W4 = (const float4*)W;
        float4* Ws4 = (float4*)&Ws[0][0];
#pragma unroll
        for (int j = 0; j < 4; j++) Ws4[tid + 256 * j] = W4[tid + 256 * j];
    }
    int row0 = blockIdx.x * 16;
    int r = tid >> 4;
    int c4 = (tid & 15) * 4;
    {
        int grow = row0 + r;
        float4 xv = make_float4(0.f, 0.f, 0.f, 0.f);
        if (grow < n) xv = *(const float4*)&X[(size_t)grow * 64 + c4];
        *(float4*)&Xs[r][c4] = xv;
    }
    __syncthreads();

    float4 acc = make_float4(0.f, 0.f, 0.f, 0.f);
#pragma unroll
    for (int k = 0; k < 64; k++) {
        float xv = Xs[r][k];
        float4 wv = *(const float4*)&Ws[k][c4];
        acc.x += xv * wv.x;
        acc.y += xv * wv.y;
        acc.z += xv * wv.z;
        acc.w += xv * wv.w;
    }
    int grow = row0 + r;
    if (grow < n) {
        float deg = 1.0f + (float)(row_ptr[grow + 1] - row_ptr[grow]);
        float dinv = rsqrtf(deg);
        __half2 h0 = __floats2half2_rn(acc.x * dinv, acc.y * dinv);
        __half2 h1 = __floats2half2_rn(acc.z * dinv, acc.w * dinv);
        uint2 pack;
        pack.x = *(const unsigned int*)&h0;
        pack.y = *(const unsigned int*)&h1;
        *(uint2*)&HS[(size_t)grow * 64 + c4] = pack;
    }
}

// ---- one wave per node; lane = feature; fp16 gathers, fp32 accumulate ----
template <bool RELU>
__global__ void k_agg(const __half* __restrict__ HS, const int* __restrict__ row_ptr,
                      const int* __restrict__ col, const float* __restrict__ bias,
                      int n, float* __restrict__ out) {
    int wave = (int)((blockIdx.x * (unsigned)blockDim.x + threadIdx.x) >> 6);
    int lane = threadIdx.x & 63;
    if (wave >= n) return;

    int r0 = row_ptr[wave];
    int r1 = row_ptr[wave + 1];

    float a0 = __half2float(HS[(size_t)wave * 64 + lane]);
    float a1 = 0.f, a2 = 0.f, a3 = 0.f;

    int e = r0;
    for (; e + 4 <= r1; e += 4) {
        int s0 = col[e + 0];
        int s1 = col[e + 1];
        int s2 = col[e + 2];
        int s3 = col[e + 3];
        a0 += __half2float(HS[(size_t)s0 * 64 + lane]);
        a1 += __half2float(HS[(size_t)s1 * 64 + lane]);
        a2 += __half2float(HS[(size_t)s2 * 64 + lane]);
        a3 += __half2float(HS[(size_t)s3 * 64 + lane]);
    }
    for (; e < r1; e++) a0 += __half2float(HS[(size_t)col[e] * 64 + lane]);

    float acc = (a0 + a1) + (a2 + a3);
    float deg = 1.0f + (float)(r1 - r0);
    float dinv = rsqrtf(deg);
    float v = dinv * acc + bias[lane];
    if (RELU) v = (v >= 0.f) ? v : 0.01f * v;
    out[(size_t)wave * 64 + lane] = v;
}

static inline size_t align256(size_t x) { return (x + 255) & ~(size_t)255; }

extern "C" void kernel_launch(void* const* d_in, const int* in_sizes, int n_in,
                              void* d_out, int out_size, void* d_ws, size_t ws_size,
                              hipStream_t stream) {
    const float* x  = (const float*)d_in[0];
    const float* W1 = (const float*)d_in[1];
    const float* b1 = (const float*)d_in[2];
    const float* W2 = (const float*)d_in[3];
    const float* b2 = (const float*)d_in[4];
    const float* W3 = (const float*)d_in[5];
    const float* b3 = (const float*)d_in[6];
    const int* edge = (const int*)d_in[7];

    int n = in_sizes[0] / 64;
    int E = in_sizes[7] / 2;
    const int* srcp = edge;
    const int* dstp = edge + E;

    int NB = (n + 255) >> SHIFT;              // buckets (391 for n=100000)
    int B1 = (E + CHUNK - 1) / CHUNK;         // histogram/scatter blocks

    char* ws = (char*)d_ws;
    int* row_ptr   = (int*)ws;      ws += align256((size_t)(n + 1) * 4);
    int* Bh        = (int*)ws;      ws += align256((size_t)B1 * NB * 4);
    int* total     = (int*)ws;      ws += align256((size_t)NB * 4);
    int* base      = (int*)ws;      ws += align256((size_t)(NB + 1) * 4);
    unsigned* ebuf = (unsigned*)ws; ws += align256((size_t)E * 4);
    int* col       = (int*)ws;      ws += align256((size_t)E * 4);
    __half* hs     = (__half*)ws;   ws += align256((size_t)n * 64 * 2);
    float* buf     = (float*)ws;    ws += align256((size_t)n * 64 * 4);
    float* out     = (float*)d_out;

    // ---- CSR build: two-level bucket sort (no global atomics) ----
    k_hist<<<B1, 256, 0, stream>>>(dstp, E, NB, Bh);
    k_bucket_scan<<<NB, 256, 0, stream>>>(Bh, B1, NB, total);
    k_base_scan<<<1, 512, 0, stream>>>(total, NB, E, base);
    k_scatter<<<B1, 256, 0, stream>>>(srcp, dstp, E, NB, Bh, base, ebuf);
    k_bucket_sort<<<NB, 256, 0, stream>>>(ebuf, base, n, E, row_ptr, col);

    int gemm_blocks = (n + 15) / 16;
    int agg_blocks  = (n + 3) / 4;

    // ---- layer 1: conv -> LeakyReLU ----
    k_gemm_scale<<<gemm_blocks, 256, 0, stream>>>(x, W1, row_ptr, n, hs);
    k_agg<true><<<agg_blocks, 256, 0, stream>>>(hs, row_ptr, col, b1, n, out);
    // ---- layer 2: conv ----
    k_gemm_scale<<<gemm_blocks, 256, 0, stream>>>(out, W2, row_ptr, n, hs);
    k_agg<false><<<agg_blocks, 256, 0, stream>>>(hs, row_ptr, col, b2, n, buf);
    // ---- layer 3: conv -> LeakyReLU ----
    k_gemm_scale<<<gemm_blocks, 256, 0, stream>>>(buf, W3, row_ptr, n, hs);
    k_agg<true><<<agg_blocks, 256, 0, stream>>>(hs, row_ptr, col, b3, n, out);
}

// Round 5
// 268.563 us; speedup vs baseline: 1.6650x; 1.1175x over previous
//
#include <hip/hip_runtime.h>
#include <hip/hip_fp16.h>
#include <math.h>

// ---------------------------------------------------------------------------
// GCN 3-layer forward on MI355X.
// Per layer (D=64):
//   hs[i,:] = fp16( dinv[i] * (x[i,:] @ W) )
//   out[i,:]= dinv[i] * (hs[i,:] + sum_{e: dst(e)=i} hs[src(e),:]) + b
//   optional LeakyReLU(0.01);   dinv[i] = rsqrt(1 + indeg(i))
//
// Round-5: k_agg restructured for 2x memory-level parallelism.
//   Wave split into two 32-lane halves; each half gathers a DIFFERENT edge's
//   fp16 row as half2/lane (one dword-gather = 2 rows = 256B). 8-edge unroll
//   gives 8 rows in flight per wave (was 4). Cross-half combine via
//   __shfl_xor(.,32); lanes 0-31 write float2.
// CSR build (round 4): atomic-free two-level bucket sort, unchanged.
// ---------------------------------------------------------------------------

constexpr int SHIFT = 8;          // bucket = dst >> 8  (256 nodes per bucket)
constexpr int CHUNK = 4096;       // edges per phase-1/scatter block

// ---- phase 1: per-block bucket histogram (block-major layout Bh[j*NB+b]) ----
__global__ void k_hist(const int* __restrict__ dst, int E, int NB,
                       int* __restrict__ Bh) {
    __shared__ int h[512];
    int tid = threadIdx.x;
    for (int i = tid; i < NB; i += 256) h[i] = 0;
    __syncthreads();
    int s = blockIdx.x * CHUNK;
    int e = min(s + CHUNK, E);
    for (int i = s + tid; i < e; i += 256) atomicAdd(&h[dst[i] >> SHIFT], 1);
    __syncthreads();
    for (int i = tid; i < NB; i += 256) Bh[(size_t)blockIdx.x * NB + i] = h[i];
}

// ---- phase 1b: per-bucket exclusive scan down the block axis ----
__global__ void k_bucket_scan(int* __restrict__ Bh, int B1, int NB,
                              int* __restrict__ total) {
    __shared__ int sh[256];
    int b = blockIdx.x;
    int tid = threadIdx.x;
    int carry = 0;
    for (int j0 = 0; j0 < B1; j0 += 256) {
        int j = j0 + tid;
        int v = (j < B1) ? Bh[(size_t)j * NB + b] : 0;
        sh[tid] = v;
        __syncthreads();
        for (int off = 1; off < 256; off <<= 1) {
            int add = (tid >= off) ? sh[tid - off] : 0;
            __syncthreads();
            sh[tid] += add;
            __syncthreads();
        }
        int excl = sh[tid] - v + carry;
        if (j < B1) Bh[(size_t)j * NB + b] = excl;
        int tot = sh[255];
        __syncthreads();
        carry += tot;
    }
    if (tid == 0) total[b] = carry;
}

// ---- phase 1c: exclusive scan of bucket totals (NB <= 512), single block ----
__global__ void k_base_scan(const int* __restrict__ total, int NB, int E,
                            int* __restrict__ base) {
    __shared__ int sh[512];
    int tid = threadIdx.x;
    int v = (tid < NB) ? total[tid] : 0;
    sh[tid] = v;
    __syncthreads();
    for (int off = 1; off < 512; off <<= 1) {
        int add = (tid >= off) ? sh[tid - off] : 0;
        __syncthreads();
        sh[tid] += add;
        __syncthreads();
    }
    if (tid < NB) base[tid] = sh[tid] - v;
    if (tid == 0) base[NB] = E;
}

// ---- phase 2: scatter packed records into bucket-contiguous ebuf ----
// record = (dst & 255) << 24 | src      (src < 2^17)
__global__ void k_scatter(const int* __restrict__ src, const int* __restrict__ dst,
                          int E, int NB, const int* __restrict__ Bh,
                          const int* __restrict__ base, unsigned* __restrict__ ebuf) {
    __shared__ int cur[512];
    int tid = threadIdx.x;
    for (int i = tid; i < NB; i += 256)
        cur[i] = base[i] + Bh[(size_t)blockIdx.x * NB + i];
    __syncthreads();
    int s = blockIdx.x * CHUNK;
    int e = min(s + CHUNK, E);
    for (int i = s + tid; i < e; i += 256) {
        int d = dst[i];
        int b = d >> SHIFT;
        int pos = atomicAdd(&cur[b], 1);
        ebuf[pos] = ((unsigned)(d & 255) << 24) | (unsigned)src[i];
    }
}

// ---- phase 3: per-bucket counting sort -> row_ptr + col ----
__global__ void k_bucket_sort(const unsigned* __restrict__ ebuf,
                              const int* __restrict__ base, int n, int E,
                              int* __restrict__ row_ptr, int* __restrict__ col) {
    __shared__ int cnt[256];
    __shared__ int sh[256];
    __shared__ int cur[256];
    int b = blockIdx.x;
    int tid = threadIdx.x;
    int s = base[b];
    int e = base[b + 1];
    cnt[tid] = 0;
    __syncthreads();
    for (int i = s + tid; i < e; i += 256) atomicAdd(&cnt[ebuf[i] >> 24], 1);
    __syncthreads();
    int c = cnt[tid];
    sh[tid] = c;
    __syncthreads();
    for (int off = 1; off < 256; off <<= 1) {
        int add = (tid >= off) ? sh[tid - off] : 0;
        __syncthreads();
        sh[tid] += add;
        __syncthreads();
    }
    int excl = sh[tid] - c;
    int node = (b << SHIFT) | tid;
    if (node < n) row_ptr[node] = s + excl;
    cur[tid] = s + excl;
    __syncthreads();
    for (int i = s + tid; i < e; i += 256) {
        unsigned v = ebuf[i];
        int pos = atomicAdd(&cur[v >> 24], 1);
        col[pos] = (int)(v & 0x00FFFFFFu);
    }
    if (b == 0 && tid == 0) row_ptr[n] = E;
}

// ---- HS[row,:] = fp16(dinv[row] * (X[row,:] @ W)), 16 rows / 256 threads ----
__global__ void k_gemm_scale(const float* __restrict__ X, const float* __restrict__ W,
                             const int* __restrict__ row_ptr, int n,
                             __half* __restrict__ HS) {
    __shared__ float Ws[64][64];
    __shared__ float Xs[16][68];
    int tid = threadIdx.x;
    {
        const float4* W4 = (const float4*)W;
        float4* Ws4 = (float4*)&Ws[0][0];
#pragma unroll
        for (int j = 0; j < 4; j++) Ws4[tid + 256 * j] = W4[tid + 256 * j];
    }
    int row0 = blockIdx.x * 16;
    int r = tid >> 4;
    int c4 = (tid & 15) * 4;
    {
        int grow = row0 + r;
        float4 xv = make_float4(0.f, 0.f, 0.f, 0.f);
        if (grow < n) xv = *(const float4*)&X[(size_t)grow * 64 + c4];
        *(float4*)&Xs[r][c4] = xv;
    }
    __syncthreads();

    float4 acc = make_float4(0.f, 0.f, 0.f, 0.f);
#pragma unroll
    for (int k = 0; k < 64; k++) {
        float xv = Xs[r][k];
        float4 wv = *(const float4*)&Ws[k][c4];
        acc.x += xv * wv.x;
        acc.y += xv * wv.y;
        acc.z += xv * wv.z;
        acc.w += xv * wv.w;
    }
    int grow = row0 + r;
    if (grow < n) {
        float deg = 1.0f + (float)(row_ptr[grow + 1] - row_ptr[grow]);
        float dinv = rsqrtf(deg);
        __half2 h0 = __floats2half2_rn(acc.x * dinv, acc.y * dinv);
        __half2 h1 = __floats2half2_rn(acc.z * dinv, acc.w * dinv);
        uint2 pack;
        pack.x = *(const unsigned int*)&h0;
        pack.y = *(const unsigned int*)&h1;
        *(uint2*)&HS[(size_t)grow * 64 + c4] = pack;
    }
}

// ---- aggregation: one wave per node, split-wave dual-row gathers ----------
// Lanes 0-31 gather even edges, lanes 32-63 odd edges; each lane loads one
// dword (half2 = features 2c,2c+1).  Cross-half combine via shfl_xor(32).
template <bool RELU>
__global__ void k_agg(const __half* __restrict__ HS, const int* __restrict__ row_ptr,
                      const int* __restrict__ col, const float* __restrict__ bias,
                      int n, float* __restrict__ out) {
    int wave = (int)((blockIdx.x * (unsigned)blockDim.x + threadIdx.x) >> 6);
    int lane = threadIdx.x & 63;
    if (wave >= n) return;

    int half = lane >> 5;   // 0: even edges, 1: odd edges
    int c    = lane & 31;   // dword index within row (features 2c, 2c+1)

    const unsigned* __restrict__ HSu = (const unsigned*)HS;

    int r0 = row_ptr[wave];
    int r1 = row_ptr[wave + 1];

    float2 a0, a1, a2, a3;
    a1 = a2 = a3 = make_float2(0.f, 0.f);
    // self term: only half 0 contributes (both halves would double-count)
    {
        unsigned v = HSu[(size_t)wave * 32 + c];
        if (half) v = 0u;
        float2 f = __half22float2(*(__half2*)&v);
        a0 = f;
    }

    int e = r0;
    for (; e + 8 <= r1; e += 8) {
        int s0 = col[e + 0 + half];
        int s1 = col[e + 2 + half];
        int s2 = col[e + 4 + half];
        int s3 = col[e + 6 + half];
        unsigned v0 = HSu[(size_t)s0 * 32 + c];
        unsigned v1 = HSu[(size_t)s1 * 32 + c];
        unsigned v2 = HSu[(size_t)s2 * 32 + c];
        unsigned v3 = HSu[(size_t)s3 * 32 + c];
        float2 f0 = __half22float2(*(__half2*)&v0);
        float2 f1 = __half22float2(*(__half2*)&v1);
        float2 f2 = __half22float2(*(__half2*)&v2);
        float2 f3 = __half22float2(*(__half2*)&v3);
        a0.x += f0.x; a0.y += f0.y;
        a1.x += f1.x; a1.y += f1.y;
        a2.x += f2.x; a2.y += f2.y;
        a3.x += f3.x; a3.y += f3.y;
    }
    for (; e + 2 <= r1; e += 2) {
        int s = col[e + half];
        unsigned v = HSu[(size_t)s * 32 + c];
        float2 f = __half22float2(*(__half2*)&v);
        a0.x += f.x; a0.y += f.y;
    }
    if (e < r1) {  // last lone edge: half 0 only
        unsigned v = HSu[(size_t)col[e] * 32 + c];
        if (half) v = 0u;
        float2 f = __half22float2(*(__half2*)&v);
        a0.x += f.x; a0.y += f.y;
    }

    float ax = (a0.x + a1.x) + (a2.x + a3.x);
    float ay = (a0.y + a1.y) + (a2.y + a3.y);
    ax += __shfl_xor(ax, 32);
    ay += __shfl_xor(ay, 32);

    if (!half) {
        float deg = 1.0f + (float)(r1 - r0);
        float dinv = rsqrtf(deg);
        float2 bv = *(const float2*)&bias[2 * c];
        float vx = dinv * ax + bv.x;
        float vy = dinv * ay + bv.y;
        if (RELU) {
            vx = (vx >= 0.f) ? vx : 0.01f * vx;
            vy = (vy >= 0.f) ? vy : 0.01f * vy;
        }
        *(float2*)&out[(size_t)wave * 64 + 2 * c] = make_float2(vx, vy);
    }
}

static inline size_t align256(size_t x) { return (x + 255) & ~(size_t)255; }

extern "C" void kernel_launch(void* const* d_in, const int* in_sizes, int n_in,
                              void* d_out, int out_size, void* d_ws, size_t ws_size,
                              hipStream_t stream) {
    const float* x  = (const float*)d_in[0];
    const float* W1 = (const float*)d_in[1];
    const float* b1 = (const float*)d_in[2];
    const float* W2 = (const float*)d_in[3];
    const float* b2 = (const float*)d_in[4];
    const float* W3 = (const float*)d_in[5];
    const float* b3 = (const float*)d_in[6];
    const int* edge = (const int*)d_in[7];

    int n = in_sizes[0] / 64;
    int E = in_sizes[7] / 2;
    const int* srcp = edge;
    const int* dstp = edge + E;

    int NB = (n + 255) >> SHIFT;              // buckets (391 for n=100000)
    int B1 = (E + CHUNK - 1) / CHUNK;         // histogram/scatter blocks

    char* ws = (char*)d_ws;
    int* row_ptr   = (int*)ws;      ws += align256((size_t)(n + 1) * 4);
    int* Bh        = (int*)ws;      ws += align256((size_t)B1 * NB * 4);
    int* total     = (int*)ws;      ws += align256((size_t)NB * 4);
    int* base      = (int*)ws;      ws += align256((size_t)(NB + 1) * 4);
    unsigned* ebuf = (unsigned*)ws; ws += align256((size_t)E * 4);
    int* col       = (int*)ws;      ws += align256((size_t)E * 4);
    __half* hs     = (__half*)ws;   ws += align256((size_t)n * 64 * 2);
    float* buf     = (float*)ws;    ws += align256((size_t)n * 64 * 4);
    float* out     = (float*)d_out;

    // ---- CSR build: two-level bucket sort (no global atomics) ----
    k_hist<<<B1, 256, 0, stream>>>(dstp, E, NB, Bh);
    k_bucket_scan<<<NB, 256, 0, stream>>>(Bh, B1, NB, total);
    k_base_scan<<<1, 512, 0, stream>>>(total, NB, E, base);
    k_scatter<<<B1, 256, 0, stream>>>(srcp, dstp, E, NB, Bh, base, ebuf);
    k_bucket_sort<<<NB, 256, 0, stream>>>(ebuf, base, n, E, row_ptr, col);

    int gemm_blocks = (n + 15) / 16;
    int agg_blocks  = (n + 3) / 4;

    // ---- layer 1: conv -> LeakyReLU ----
    k_gemm_scale<<<gemm_blocks, 256, 0, stream>>>(x, W1, row_ptr, n, hs);
    k_agg<true><<<agg_blocks, 256, 0, stream>>>(hs, row_ptr, col, b1, n, out);
    // ---- layer 2: conv ----
    k_gemm_scale<<<gemm_blocks, 256, 0, stream>>>(out, W2, row_ptr, n, hs);
    k_agg<false><<<agg_blocks, 256, 0, stream>>>(hs, row_ptr, col, b2, n, buf);
    // ---- layer 3: conv -> LeakyReLU ----
    k_gemm_scale<<<gemm_blocks, 256, 0, stream>>>(buf, W3, row_ptr, n, hs);
    k_agg<true><<<agg_blocks, 256, 0, stream>>>(hs, row_ptr, col, b3, n, out);
}

// Round 6
// 259.243 us; speedup vs baseline: 1.7248x; 1.0360x over previous
//
#include <hip/hip_runtime.h>
#include <hip/hip_fp16.h>
#include <math.h>

// ---------------------------------------------------------------------------
// GCN 3-layer forward on MI355X.
// Per layer (D=64):
//   hs[i,:] = fp16( dinv[i] * (x[i,:] @ W) )
//   out[i,:]= dinv[i] * (hs[i,:] + sum_{e: dst(e)=i} hs[src(e),:]) + b
//   optional LeakyReLU(0.01);   dinv[i] = rsqrt(1 + indeg(i))
//
// Round-6: k_agg with four 16-lane groups per wave.
//   Each group gathers a DIFFERENT edge's row; lane loads uint2 (4 fp16
//   features), so one gather instr = 4 edges x 128B. 16-edge unroll keeps
//   4 gathers (16 edges) in flight; the tail covers 4 edges per instr.
//   Cross-group combine via shfl_xor(16/32); lanes 0-15 write float4.
// CSR build (round 4): atomic-free two-level bucket sort, unchanged.
// ---------------------------------------------------------------------------

constexpr int SHIFT = 8;          // bucket = dst >> 8  (256 nodes per bucket)
constexpr int CHUNK = 4096;       // edges per phase-1/scatter block

// ---- phase 1: per-block bucket histogram (block-major layout Bh[j*NB+b]) ----
__global__ void k_hist(const int* __restrict__ dst, int E, int NB,
                       int* __restrict__ Bh) {
    __shared__ int h[512];
    int tid = threadIdx.x;
    for (int i = tid; i < NB; i += 256) h[i] = 0;
    __syncthreads();
    int s = blockIdx.x * CHUNK;
    int e = min(s + CHUNK, E);
    for (int i = s + tid; i < e; i += 256) atomicAdd(&h[dst[i] >> SHIFT], 1);
    __syncthreads();
    for (int i = tid; i < NB; i += 256) Bh[(size_t)blockIdx.x * NB + i] = h[i];
}

// ---- phase 1b: per-bucket exclusive scan down the block axis ----
__global__ void k_bucket_scan(int* __restrict__ Bh, int B1, int NB,
                              int* __restrict__ total) {
    __shared__ int sh[256];
    int b = blockIdx.x;
    int tid = threadIdx.x;
    int carry = 0;
    for (int j0 = 0; j0 < B1; j0 += 256) {
        int j = j0 + tid;
        int v = (j < B1) ? Bh[(size_t)j * NB + b] : 0;
        sh[tid] = v;
        __syncthreads();
        for (int off = 1; off < 256; off <<= 1) {
            int add = (tid >= off) ? sh[tid - off] : 0;
            __syncthreads();
            sh[tid] += add;
            __syncthreads();
        }
        int excl = sh[tid] - v + carry;
        if (j < B1) Bh[(size_t)j * NB + b] = excl;
        int tot = sh[255];
        __syncthreads();
        carry += tot;
    }
    if (tid == 0) total[b] = carry;
}

// ---- phase 1c: exclusive scan of bucket totals (NB <= 512), single block ----
__global__ void k_base_scan(const int* __restrict__ total, int NB, int E,
                            int* __restrict__ base) {
    __shared__ int sh[512];
    int tid = threadIdx.x;
    int v = (tid < NB) ? total[tid] : 0;
    sh[tid] = v;
    __syncthreads();
    for (int off = 1; off < 512; off <<= 1) {
        int add = (tid >= off) ? sh[tid - off] : 0;
        __syncthreads();
        sh[tid] += add;
        __syncthreads();
    }
    if (tid < NB) base[tid] = sh[tid] - v;
    if (tid == 0) base[NB] = E;
}

// ---- phase 2: scatter packed records into bucket-contiguous ebuf ----
// record = (dst & 255) << 24 | src      (src < 2^17)
__global__ void k_scatter(const int* __restrict__ src, const int* __restrict__ dst,
                          int E, int NB, const int* __restrict__ Bh,
                          const int* __restrict__ base, unsigned* __restrict__ ebuf) {
    __shared__ int cur[512];
    int tid = threadIdx.x;
    for (int i = tid; i < NB; i += 256)
        cur[i] = base[i] + Bh[(size_t)blockIdx.x * NB + i];
    __syncthreads();
    int s = blockIdx.x * CHUNK;
    int e = min(s + CHUNK, E);
    for (int i = s + tid; i < e; i += 256) {
        int d = dst[i];
        int b = d >> SHIFT;
        int pos = atomicAdd(&cur[b], 1);
        ebuf[pos] = ((unsigned)(d & 255) << 24) | (unsigned)src[i];
    }
}

// ---- phase 3: per-bucket counting sort -> row_ptr + col ----
__global__ void k_bucket_sort(const unsigned* __restrict__ ebuf,
                              const int* __restrict__ base, int n, int E,
                              int* __restrict__ row_ptr, int* __restrict__ col) {
    __shared__ int cnt[256];
    __shared__ int sh[256];
    __shared__ int cur[256];
    int b = blockIdx.x;
    int tid = threadIdx.x;
    int s = base[b];
    int e = base[b + 1];
    cnt[tid] = 0;
    __syncthreads();
    for (int i = s + tid; i < e; i += 256) atomicAdd(&cnt[ebuf[i] >> 24], 1);
    __syncthreads();
    int c = cnt[tid];
    sh[tid] = c;
    __syncthreads();
    for (int off = 1; off < 256; off <<= 1) {
        int add = (tid >= off) ? sh[tid - off] : 0;
        __syncthreads();
        sh[tid] += add;
        __syncthreads();
    }
    int excl = sh[tid] - c;
    int node = (b << SHIFT) | tid;
    if (node < n) row_ptr[node] = s + excl;
    cur[tid] = s + excl;
    __syncthreads();
    for (int i = s + tid; i < e; i += 256) {
        unsigned v = ebuf[i];
        int pos = atomicAdd(&cur[v >> 24], 1);
        col[pos] = (int)(v & 0x00FFFFFFu);
    }
    if (b == 0 && tid == 0) row_ptr[n] = E;
}

// ---- HS[row,:] = fp16(dinv[row] * (X[row,:] @ W)), 16 rows / 256 threads ----
__global__ void k_gemm_scale(const float* __restrict__ X, const float* __restrict__ W,
                             const int* __restrict__ row_ptr, int n,
                             __half* __restrict__ HS) {
    __shared__ float Ws[64][64];
    __shared__ float Xs[16][68];
    int tid = threadIdx.x;
    {
        const float4* W4 = (const float4*)W;
        float4* Ws4 = (float4*)&Ws[0][0];
#pragma unroll
        for (int j = 0; j < 4; j++) Ws4[tid + 256 * j] = W4[tid + 256 * j];
    }
    int row0 = blockIdx.x * 16;
    int r = tid >> 4;
    int c4 = (tid & 15) * 4;
    {
        int grow = row0 + r;
        float4 xv = make_float4(0.f, 0.f, 0.f, 0.f);
        if (grow < n) xv = *(const float4*)&X[(size_t)grow * 64 + c4];
        *(float4*)&Xs[r][c4] = xv;
    }
    __syncthreads();

    float4 acc = make_float4(0.f, 0.f, 0.f, 0.f);
#pragma unroll
    for (int k = 0; k < 64; k++) {
        float xv = Xs[r][k];
        float4 wv = *(const float4*)&Ws[k][c4];
        acc.x += xv * wv.x;
        acc.y += xv * wv.y;
        acc.z += xv * wv.z;
        acc.w += xv * wv.w;
    }
    int grow = row0 + r;
    if (grow < n) {
        float deg = 1.0f + (float)(row_ptr[grow + 1] - row_ptr[grow]);
        float dinv = rsqrtf(deg);
        __half2 h0 = __floats2half2_rn(acc.x * dinv, acc.y * dinv);
        __half2 h1 = __floats2half2_rn(acc.z * dinv, acc.w * dinv);
        uint2 pack;
        pack.x = *(const unsigned int*)&h0;
        pack.y = *(const unsigned int*)&h1;
        *(uint2*)&HS[(size_t)grow * 64 + c4] = pack;
    }
}

__device__ inline float4 cvt_h4(uint2 v) {
    float2 f0 = __half22float2(*(__half2*)&v.x);
    float2 f1 = __half22float2(*(__half2*)&v.y);
    return make_float4(f0.x, f0.y, f1.x, f1.y);
}

// ---- aggregation: one wave per node, four 16-lane groups -------------------
// Group g handles edges e+g, e+4+g, e+8+g, e+12+g; lane loads uint2
// (features 4c..4c+3).  One gather instr = 4 edges x 128B row.
template <bool RELU>
__global__ void k_agg(const __half* __restrict__ HS, const int* __restrict__ row_ptr,
                      const int* __restrict__ col, const float* __restrict__ bias,
                      int n, float* __restrict__ out) {
    int wave = (int)((blockIdx.x * (unsigned)blockDim.x + threadIdx.x) >> 6);
    int lane = threadIdx.x & 63;
    if (wave >= n) return;

    int g = lane >> 4;    // edge group 0..3
    int c = lane & 15;    // uint2 index within row (features 4c..4c+3)

    const uint2* __restrict__ HSu = (const uint2*)HS;

    int r0 = row_ptr[wave];
    int r1 = row_ptr[wave + 1];

    float4 a0 = make_float4(0.f, 0.f, 0.f, 0.f);
    float4 a1 = a0, a2 = a0, a3 = a0;

    // self term: group 0 only
    if (g == 0) a0 = cvt_h4(HSu[(size_t)wave * 16 + c]);

    int e = r0;
    for (; e + 16 <= r1; e += 16) {
        int s0 = col[e + g];
        int s1 = col[e + 4 + g];
        int s2 = col[e + 8 + g];
        int s3 = col[e + 12 + g];
        uint2 v0 = HSu[(size_t)s0 * 16 + c];
        uint2 v1 = HSu[(size_t)s1 * 16 + c];
        uint2 v2 = HSu[(size_t)s2 * 16 + c];
        uint2 v3 = HSu[(size_t)s3 * 16 + c];
        float4 f0 = cvt_h4(v0);
        float4 f1 = cvt_h4(v1);
        float4 f2 = cvt_h4(v2);
        float4 f3 = cvt_h4(v3);
        a0.x += f0.x; a0.y += f0.y; a0.z += f0.z; a0.w += f0.w;
        a1.x += f1.x; a1.y += f1.y; a1.z += f1.z; a1.w += f1.w;
        a2.x += f2.x; a2.y += f2.y; a2.z += f2.z; a2.w += f2.w;
        a3.x += f3.x; a3.y += f3.y; a3.z += f3.z; a3.w += f3.w;
    }
    for (; e < r1; e += 4) {
        int idx = e + g;
        if (idx < r1) {
            float4 f = cvt_h4(HSu[(size_t)col[idx] * 16 + c]);
            a0.x += f.x; a0.y += f.y; a0.z += f.z; a0.w += f.w;
        }
    }

    float4 s;
    s.x = (a0.x + a1.x) + (a2.x + a3.x);
    s.y = (a0.y + a1.y) + (a2.y + a3.y);
    s.z = (a0.z + a1.z) + (a2.z + a3.z);
    s.w = (a0.w + a1.w) + (a2.w + a3.w);
    s.x += __shfl_xor(s.x, 16); s.y += __shfl_xor(s.y, 16);
    s.z += __shfl_xor(s.z, 16); s.w += __shfl_xor(s.w, 16);
    s.x += __shfl_xor(s.x, 32); s.y += __shfl_xor(s.y, 32);
    s.z += __shfl_xor(s.z, 32); s.w += __shfl_xor(s.w, 32);

    if (lane < 16) {
        float deg = 1.0f + (float)(r1 - r0);
        float dinv = rsqrtf(deg);
        float4 bv = *(const float4*)&bias[4 * c];
        float vx = dinv * s.x + bv.x;
        float vy = dinv * s.y + bv.y;
        float vz = dinv * s.z + bv.z;
        float vw = dinv * s.w + bv.w;
        if (RELU) {
            vx = (vx >= 0.f) ? vx : 0.01f * vx;
            vy = (vy >= 0.f) ? vy : 0.01f * vy;
            vz = (vz >= 0.f) ? vz : 0.01f * vz;
            vw = (vw >= 0.f) ? vw : 0.01f * vw;
        }
        *(float4*)&out[(size_t)wave * 64 + 4 * c] = make_float4(vx, vy, vz, vw);
    }
}

static inline size_t align256(size_t x) { return (x + 255) & ~(size_t)255; }

extern "C" void kernel_launch(void* const* d_in, const int* in_sizes, int n_in,
                              void* d_out, int out_size, void* d_ws, size_t ws_size,
                              hipStream_t stream) {
    const float* x  = (const float*)d_in[0];
    const float* W1 = (const float*)d_in[1];
    const float* b1 = (const float*)d_in[2];
    const float* W2 = (const float*)d_in[3];
    const float* b2 = (const float*)d_in[4];
    const float* W3 = (const float*)d_in[5];
    const float* b3 = (const float*)d_in[6];
    const int* edge = (const int*)d_in[7];

    int n = in_sizes[0] / 64;
    int E = in_sizes[7] / 2;
    const int* srcp = edge;
    const int* dstp = edge + E;

    int NB = (n + 255) >> SHIFT;              // buckets (391 for n=100000)
    int B1 = (E + CHUNK - 1) / CHUNK;         // histogram/scatter blocks

    char* ws = (char*)d_ws;
    int* row_ptr   = (int*)ws;      ws += align256((size_t)(n + 1) * 4);
    int* Bh        = (int*)ws;      ws += align256((size_t)B1 * NB * 4);
    int* total     = (int*)ws;      ws += align256((size_t)NB * 4);
    int* base      = (int*)ws;      ws += align256((size_t)(NB + 1) * 4);
    unsigned* ebuf = (unsigned*)ws; ws += align256((size_t)E * 4);
    int* col       = (int*)ws;      ws += align256((size_t)E * 4);
    __half* hs     = (__half*)ws;   ws += align256((size_t)n * 64 * 2);
    float* buf     = (float*)ws;    ws += align256((size_t)n * 64 * 4);
    float* out     = (float*)d_out;

    // ---- CSR build: two-level bucket sort (no global atomics) ----
    k_hist<<<B1, 256, 0, stream>>>(dstp, E, NB, Bh);
    k_bucket_scan<<<NB, 256, 0, stream>>>(Bh, B1, NB, total);
    k_base_scan<<<1, 512, 0, stream>>>(total, NB, E, base);
    k_scatter<<<B1, 256, 0, stream>>>(srcp, dstp, E, NB, Bh, base, ebuf);
    k_bucket_sort<<<NB, 256, 0, stream>>>(ebuf, base, n, E, row_ptr, col);

    int gemm_blocks = (n + 15) / 16;
    int agg_blocks  = (n + 3) / 4;

    // ---- layer 1: conv -> LeakyReLU ----
    k_gemm_scale<<<gemm_blocks, 256, 0, stream>>>(x, W1, row_ptr, n, hs);
    k_agg<true><<<agg_blocks, 256, 0, stream>>>(hs, row_ptr, col, b1, n, out);
    // ---- layer 2: conv ----
    k_gemm_scale<<<gemm_blocks, 256, 0, stream>>>(out, W2, row_ptr, n, hs);
    k_agg<false><<<agg_blocks, 256, 0, stream>>>(hs, row_ptr, col, b2, n, buf);
    // ---- layer 3: conv -> LeakyReLU ----
    k_gemm_scale<<<gemm_blocks, 256, 0, stream>>>(buf, W3, row_ptr, n, hs);
    k_agg<true><<<agg_blocks, 256, 0, stream>>>(hs, row_ptr, col, b3, n, out);
}

// Round 7
// 254.209 us; speedup vs baseline: 1.7590x; 1.0198x over previous
//
#include <hip/hip_runtime.h>
#include <hip/hip_fp16.h>
#include <math.h>

// ---------------------------------------------------------------------------
// GCN 3-layer forward on MI355X.
// Per layer (D=64):
//   hs[i,:] = fp16( dinv[i] * (x[i,:] @ W) )
//   out[i,:]= dinv[i] * (hs[i,:] + sum_{e: dst(e)=i} hs[src(e),:]) + b
//   optional LeakyReLU(0.01);   dinv[i] = rsqrt(1 + indeg(i))
//
// Round-7: kill partial-line write amplification in the CSR build.
//   k_scatter now LDS-counting-sorts its 4096-edge chunk by bucket and writes
//   contiguous per-(block,bucket) runs (avg 10.5 edges -> line-merged), instead
//   of 4B random scatters into 16KB windows (which wrote ~64B/line like r1's
//   k_fill).  k_bucket_sort stages the whole bucket in LDS and writes col
//   coalesced.  k_agg unchanged: it sits at the per-CU VMEM request ceiling
//   (~1 line-request / 9 cyc / CU across r4/r5/r6 variants).
// ---------------------------------------------------------------------------

constexpr int SHIFT = 8;          // bucket = dst >> 8  (256 nodes per bucket)
constexpr int CHUNK = 4096;       // edges per phase-1/scatter block
constexpr int BCAP  = 5120;       // bucket staging capacity (mean 4096, sd 64)

// ---- phase 1: per-block bucket histogram (block-major layout Bh[j*NB+b]) ----
__global__ void k_hist(const int* __restrict__ dst, int E, int NB,
                       int* __restrict__ Bh) {
    __shared__ int h[512];
    int tid = threadIdx.x;
    for (int i = tid; i < 512; i += 256) h[i] = 0;
    __syncthreads();
    int s = blockIdx.x * CHUNK;
    int e = min(s + CHUNK, E);
    for (int i = s + tid; i < e; i += 256) atomicAdd(&h[dst[i] >> SHIFT], 1);
    __syncthreads();
    for (int i = tid; i < NB; i += 256) Bh[(size_t)blockIdx.x * NB + i] = h[i];
}

// ---- phase 1b: per-bucket exclusive scan down the block axis ----
__global__ void k_bucket_scan(int* __restrict__ Bh, int B1, int NB,
                              int* __restrict__ total) {
    __shared__ int sh[256];
    int b = blockIdx.x;
    int tid = threadIdx.x;
    int carry = 0;
    for (int j0 = 0; j0 < B1; j0 += 256) {
        int j = j0 + tid;
        int v = (j < B1) ? Bh[(size_t)j * NB + b] : 0;
        sh[tid] = v;
        __syncthreads();
        for (int off = 1; off < 256; off <<= 1) {
            int add = (tid >= off) ? sh[tid - off] : 0;
            __syncthreads();
            sh[tid] += add;
            __syncthreads();
        }
        int excl = sh[tid] - v + carry;
        if (j < B1) Bh[(size_t)j * NB + b] = excl;
        int tot = sh[255];
        __syncthreads();
        carry += tot;
    }
    if (tid == 0) total[b] = carry;
}

// ---- phase 1c: exclusive scan of bucket totals (NB <= 512), single block ----
__global__ void k_base_scan(const int* __restrict__ total, int NB, int E,
                            int* __restrict__ base) {
    __shared__ int sh[512];
    int tid = threadIdx.x;
    int v = (tid < NB) ? total[tid] : 0;
    sh[tid] = v;
    __syncthreads();
    for (int off = 1; off < 512; off <<= 1) {
        int add = (tid >= off) ? sh[tid - off] : 0;
        __syncthreads();
        sh[tid] += add;
        __syncthreads();
    }
    if (tid < NB) base[tid] = sh[tid] - v;
    if (tid == 0) base[NB] = E;
}

// ---- phase 2: LDS-binned scatter of packed records into ebuf ----
// record = (dst & 255) << 24 | src      (src < 2^17)
// Local counting sort by bucket, then contiguous-run writes: block j's edges
// for bucket b land at [base[b]+Bh[j][b], ...) sequentially.
__global__ void k_scatter(const int* __restrict__ src, const int* __restrict__ dst,
                          int E, int NB, const int* __restrict__ Bh,
                          const int* __restrict__ base, unsigned* __restrict__ ebuf) {
    __shared__ int h[512];              // counts -> local exclusive scan
    __shared__ int cur[512];            // running cursor
    __shared__ int gb[512];             // global write offset minus local scan
    __shared__ int sh[256];
    __shared__ unsigned srec[CHUNK];    // records sorted by bucket
    __shared__ int spos[CHUNK];         // global positions
    int tid = threadIdx.x;
    for (int i = tid; i < 512; i += 256) h[i] = 0;
    __syncthreads();
    int s = blockIdx.x * CHUNK;
    int e = min(s + CHUNK, E);
    // A: local histogram
    for (int i = s + tid; i < e; i += 256) atomicAdd(&h[dst[i] >> SHIFT], 1);
    __syncthreads();
    // B: exclusive scan of h[0..511] with 256 threads (2 parts)
    int carry = 0;
    for (int part = 0; part < 2; part++) {
        int idx = part * 256 + tid;
        int v = h[idx];
        sh[tid] = v;
        __syncthreads();
        for (int off = 1; off < 256; off <<= 1) {
            int add = (tid >= off) ? sh[tid - off] : 0;
            __syncthreads();
            sh[tid] += add;
            __syncthreads();
        }
        int excl = sh[tid] - v + carry;
        int tot = sh[255];
        __syncthreads();
        h[idx] = excl;
        carry += tot;
        __syncthreads();
    }
    for (int b = tid; b < NB; b += 256) {
        cur[b] = h[b];
        gb[b]  = base[b] + Bh[(size_t)blockIdx.x * NB + b] - h[b];
    }
    __syncthreads();
    // C: place into LDS sorted by bucket, record global position
    for (int i = s + tid; i < e; i += 256) {
        int d = dst[i];
        int b = d >> SHIFT;
        unsigned rec = ((unsigned)(d & 255) << 24) | (unsigned)src[i];
        int lpos = atomicAdd(&cur[b], 1);
        srec[lpos] = rec;
        spos[lpos] = gb[b] + lpos;
    }
    __syncthreads();
    // D: contiguous-run writes (runs avg ~10.5 edges -> line-merged)
    int cntE = e - s;
    for (int t = tid; t < cntE; t += 256) ebuf[spos[t]] = srec[t];
}

// ---- phase 3: per-bucket counting sort -> row_ptr + col (staged in LDS) ----
__global__ void k_bucket_sort(const unsigned* __restrict__ ebuf,
                              const int* __restrict__ base, int n, int E,
                              int* __restrict__ row_ptr, int* __restrict__ col) {
    __shared__ int cnt[256];
    __shared__ int sh[256];
    __shared__ int cur[256];
    __shared__ unsigned srec[BCAP];
    int b = blockIdx.x;
    int tid = threadIdx.x;
    int s = base[b];
    int e = base[b + 1];
    int len = e - s;
    cnt[tid] = 0;
    __syncthreads();
    for (int i = s + tid; i < e; i += 256) atomicAdd(&cnt[ebuf[i] >> 24], 1);
    __syncthreads();
    int c = cnt[tid];
    sh[tid] = c;
    __syncthreads();
    for (int off = 1; off < 256; off <<= 1) {
        int add = (tid >= off) ? sh[tid - off] : 0;
        __syncthreads();
        sh[tid] += add;
        __syncthreads();
    }
    int excl = sh[tid] - c;
    int node = (b << SHIFT) | tid;
    if (node < n) row_ptr[node] = s + excl;
    cur[tid] = excl;                 // local cursor
    __syncthreads();
    if (len <= BCAP) {
        for (int i = s + tid; i < e; i += 256) {
            unsigned v = ebuf[i];
            int lpos = atomicAdd(&cur[v >> 24], 1);
            srec[lpos] = v & 0x00FFFFFFu;
        }
        __syncthreads();
        for (int t = tid; t < len; t += 256) col[s + t] = (int)srec[t];
    } else {  // statistical impossibility guard: unstaged scatter
        for (int i = s + tid; i < e; i += 256) {
            unsigned v = ebuf[i];
            int lpos = atomicAdd(&cur[v >> 24], 1);
            col[s + lpos] = (int)(v & 0x00FFFFFFu);
        }
    }
    if (b == 0 && tid == 0) row_ptr[n] = E;
}

// ---- HS[row,:] = fp16(dinv[row] * (X[row,:] @ W)), 16 rows / 256 threads ----
__global__ void k_gemm_scale(const float* __restrict__ X, const float* __restrict__ W,
                             const int* __restrict__ row_ptr, int n,
                             __half* __restrict__ HS) {
    __shared__ float Ws[64][64];
    __shared__ float Xs[16][68];
    int tid = threadIdx.x;
    {
        const float4* W4 = (const float4*)W;
        float4* Ws4 = (float4*)&Ws[0][0];
#pragma unroll
        for (int j = 0; j < 4; j++) Ws4[tid + 256 * j] = W4[tid + 256 * j];
    }
    int row0 = blockIdx.x * 16;
    int r = tid >> 4;
    int c4 = (tid & 15) * 4;
    {
        int grow = row0 + r;
        float4 xv = make_float4(0.f, 0.f, 0.f, 0.f);
        if (grow < n) xv = *(const float4*)&X[(size_t)grow * 64 + c4];
        *(float4*)&Xs[r][c4] = xv;
    }
    __syncthreads();

    float4 acc = make_float4(0.f, 0.f, 0.f, 0.f);
#pragma unroll
    for (int k = 0; k < 64; k++) {
        float xv = Xs[r][k];
        float4 wv = *(const float4*)&Ws[k][c4];
        acc.x += xv * wv.x;
        acc.y += xv * wv.y;
        acc.z += xv * wv.z;
        acc.w += xv * wv.w;
    }
    int grow = row0 + r;
    if (grow < n) {
        float deg = 1.0f + (float)(row_ptr[grow + 1] - row_ptr[grow]);
        float dinv = rsqrtf(deg);
        __half2 h0 = __floats2half2_rn(acc.x * dinv, acc.y * dinv);
        __half2 h1 = __floats2half2_rn(acc.z * dinv, acc.w * dinv);
        uint2 pack;
        pack.x = *(const unsigned int*)&h0;
        pack.y = *(const unsigned int*)&h1;
        *(uint2*)&HS[(size_t)grow * 64 + c4] = pack;
    }
}

__device__ inline float4 cvt_h4(uint2 v) {
    float2 f0 = __half22float2(*(__half2*)&v.x);
    float2 f1 = __half22float2(*(__half2*)&v.y);
    return make_float4(f0.x, f0.y, f1.x, f1.y);
}

// ---- aggregation: one wave per node, four 16-lane groups -------------------
// Group g handles edges e+g, e+4+g, e+8+g, e+12+g; lane loads uint2
// (features 4c..4c+3).  One gather instr = 4 edges x 128B row.
template <bool RELU>
__global__ void k_agg(const __half* __restrict__ HS, const int* __restrict__ row_ptr,
                      const int* __restrict__ col, const float* __restrict__ bias,
                      int n, float* __restrict__ out) {
    int wave = (int)((blockIdx.x * (unsigned)blockDim.x + threadIdx.x) >> 6);
    int lane = threadIdx.x & 63;
    if (wave >= n) return;

    int g = lane >> 4;    // edge group 0..3
    int c = lane & 15;    // uint2 index within row (features 4c..4c+3)

    const uint2* __restrict__ HSu = (const uint2*)HS;

    int r0 = row_ptr[wave];
    int r1 = row_ptr[wave + 1];

    float4 a0 = make_float4(0.f, 0.f, 0.f, 0.f);
    float4 a1 = a0, a2 = a0, a3 = a0;

    // self term: group 0 only
    if (g == 0) a0 = cvt_h4(HSu[(size_t)wave * 16 + c]);

    int e = r0;
    for (; e + 16 <= r1; e += 16) {
        int s0 = col[e + g];
        int s1 = col[e + 4 + g];
        int s2 = col[e + 8 + g];
        int s3 = col[e + 12 + g];
        uint2 v0 = HSu[(size_t)s0 * 16 + c];
        uint2 v1 = HSu[(size_t)s1 * 16 + c];
        uint2 v2 = HSu[(size_t)s2 * 16 + c];
        uint2 v3 = HSu[(size_t)s3 * 16 + c];
        float4 f0 = cvt_h4(v0);
        float4 f1 = cvt_h4(v1);
        float4 f2 = cvt_h4(v2);
        float4 f3 = cvt_h4(v3);
        a0.x += f0.x; a0.y += f0.y; a0.z += f0.z; a0.w += f0.w;
        a1.x += f1.x; a1.y += f1.y; a1.z += f1.z; a1.w += f1.w;
        a2.x += f2.x; a2.y += f2.y; a2.z += f2.z; a2.w += f2.w;
        a3.x += f3.x; a3.y += f3.y; a3.z += f3.z; a3.w += f3.w;
    }
    for (; e < r1; e += 4) {
        int idx = e + g;
        if (idx < r1) {
            float4 f = cvt_h4(HSu[(size_t)col[idx] * 16 + c]);
            a0.x += f.x; a0.y += f.y; a0.z += f.z; a0.w += f.w;
        }
    }

    float4 s;
    s.x = (a0.x + a1.x) + (a2.x + a3.x);
    s.y = (a0.y + a1.y) + (a2.y + a3.y);
    s.z = (a0.z + a1.z) + (a2.z + a3.z);
    s.w = (a0.w + a1.w) + (a2.w + a3.w);
    s.x += __shfl_xor(s.x, 16); s.y += __shfl_xor(s.y, 16);
    s.z += __shfl_xor(s.z, 16); s.w += __shfl_xor(s.w, 16);
    s.x += __shfl_xor(s.x, 32); s.y += __shfl_xor(s.y, 32);
    s.z += __shfl_xor(s.z, 32); s.w += __shfl_xor(s.w, 32);

    if (lane < 16) {
        float deg = 1.0f + (float)(r1 - r0);
        float dinv = rsqrtf(deg);
        float4 bv = *(const float4*)&bias[4 * c];
        float vx = dinv * s.x + bv.x;
        float vy = dinv * s.y + bv.y;
        float vz = dinv * s.z + bv.z;
        float vw = dinv * s.w + bv.w;
        if (RELU) {
            vx = (vx >= 0.f) ? vx : 0.01f * vx;
            vy = (vy >= 0.f) ? vy : 0.01f * vy;
            vz = (vz >= 0.f) ? vz : 0.01f * vz;
            vw = (vw >= 0.f) ? vw : 0.01f * vw;
        }
        *(float4*)&out[(size_t)wave * 64 + 4 * c] = make_float4(vx, vy, vz, vw);
    }
}

static inline size_t align256(size_t x) { return (x + 255) & ~(size_t)255; }

extern "C" void kernel_launch(void* const* d_in, const int* in_sizes, int n_in,
                              void* d_out, int out_size, void* d_ws, size_t ws_size,
                              hipStream_t stream) {
    const float* x  = (const float*)d_in[0];
    const float* W1 = (const float*)d_in[1];
    const float* b1 = (const float*)d_in[2];
    const float* W2 = (const float*)d_in[3];
    const float* b2 = (const float*)d_in[4];
    const float* W3 = (const float*)d_in[5];
    const float* b3 = (const float*)d_in[6];
    const int* edge = (const int*)d_in[7];

    int n = in_sizes[0] / 64;
    int E = in_sizes[7] / 2;
    const int* srcp = edge;
    const int* dstp = edge + E;

    int NB = (n + 255) >> SHIFT;              // buckets (391 for n=100000)
    int B1 = (E + CHUNK - 1) / CHUNK;         // histogram/scatter blocks

    char* ws = (char*)d_ws;
    int* row_ptr   = (int*)ws;      ws += align256((size_t)(n + 1) * 4);
    int* Bh        = (int*)ws;      ws += align256((size_t)B1 * NB * 4);
    int* total     = (int*)ws;      ws += align256((size_t)NB * 4);
    int* base      = (int*)ws;      ws += align256((size_t)(NB + 1) * 4);
    unsigned* ebuf = (unsigned*)ws; ws += align256((size_t)E * 4);
    int* col       = (int*)ws;      ws += align256((size_t)E * 4);
    __half* hs     = (__half*)ws;   ws += align256((size_t)n * 64 * 2);
    float* buf     = (float*)ws;    ws += align256((size_t)n * 64 * 4);
    float* out     = (float*)d_out;

    // ---- CSR build: two-level bucket sort (LDS-binned writes) ----
    k_hist<<<B1, 256, 0, stream>>>(dstp, E, NB, Bh);
    k_bucket_scan<<<NB, 256, 0, stream>>>(Bh, B1, NB, total);
    k_base_scan<<<1, 512, 0, stream>>>(total, NB, E, base);
    k_scatter<<<B1, 256, 0, stream>>>(srcp, dstp, E, NB, Bh, base, ebuf);
    k_bucket_sort<<<NB, 256, 0, stream>>>(ebuf, base, n, E, row_ptr, col);

    int gemm_blocks = (n + 15) / 16;
    int agg_blocks  = (n + 3) / 4;

    // ---- layer 1: conv -> LeakyReLU ----
    k_gemm_scale<<<gemm_blocks, 256, 0, stream>>>(x, W1, row_ptr, n, hs);
    k_agg<true><<<agg_blocks, 256, 0, stream>>>(hs, row_ptr, col, b1, n, out);
    // ---- layer 2: conv ----
    k_gemm_scale<<<gemm_blocks, 256, 0, stream>>>(out, W2, row_ptr, n, hs);
    k_agg<false><<<agg_blocks, 256, 0, stream>>>(hs, row_ptr, col, b2, n, buf);
    // ---- layer 3: conv -> LeakyReLU ----
    k_gemm_scale<<<gemm_blocks, 256, 0, stream>>>(buf, W3, row_ptr, n, hs);
    k_agg<true><<<agg_blocks, 256, 0, stream>>>(hs, row_ptr, col, b3, n, out);
}

// Round 8
// 206.040 us; speedup vs baseline: 2.1702x; 1.2338x over previous
//
#include <hip/hip_runtime.h>
#include <hip/hip_fp16.h>
#include <math.h>

// ---------------------------------------------------------------------------
// GCN 3-layer forward on MI355X.
// Per layer (D=64):
//   hs[i,:] = fp16( dinv[i] * (x[i,:] @ W) )
//   out[i,:]= dinv[i] * (hs[i,:] + sum_{e: dst(e)=i} hs[src(e),:]) + b
//   optional LeakyReLU(0.01);   dinv[i] = rsqrt(1 + indeg(i))
//
// Round-8: k_agg = one 16-lane group per node (4 nodes/wave, independent).
//   Poisson(16) degrees meant ~50% of rows ran the old 4-edge tail with
//   MLP=1.  Now each group walks its own row 8-at-a-time (8 gathers in
//   flight), then a 4-batch, then PREDICATED singles (still 1 latency unit).
//   col[] stores byte offsets (src*128) to kill per-gather v_mul.
// CSR build: two-level bucket sort with LDS-binned writes (round 7).
// ---------------------------------------------------------------------------

constexpr int SHIFT = 8;          // bucket = dst >> 8  (256 nodes per bucket)
constexpr int CHUNK = 4096;       // edges per phase-1/scatter block
constexpr int BCAP  = 5120;       // bucket staging capacity (mean 4096, sd 64)

// ---- phase 1: per-block bucket histogram (block-major layout Bh[j*NB+b]) ----
__global__ void k_hist(const int* __restrict__ dst, int E, int NB,
                       int* __restrict__ Bh) {
    __shared__ int h[512];
    int tid = threadIdx.x;
    for (int i = tid; i < 512; i += 256) h[i] = 0;
    __syncthreads();
    int s = blockIdx.x * CHUNK;
    int e = min(s + CHUNK, E);
    for (int i = s + tid; i < e; i += 256) atomicAdd(&h[dst[i] >> SHIFT], 1);
    __syncthreads();
    for (int i = tid; i < NB; i += 256) Bh[(size_t)blockIdx.x * NB + i] = h[i];
}

// ---- phase 1b: per-bucket exclusive scan down the block axis ----
__global__ void k_bucket_scan(int* __restrict__ Bh, int B1, int NB,
                              int* __restrict__ total) {
    __shared__ int sh[256];
    int b = blockIdx.x;
    int tid = threadIdx.x;
    int carry = 0;
    for (int j0 = 0; j0 < B1; j0 += 256) {
        int j = j0 + tid;
        int v = (j < B1) ? Bh[(size_t)j * NB + b] : 0;
        sh[tid] = v;
        __syncthreads();
        for (int off = 1; off < 256; off <<= 1) {
            int add = (tid >= off) ? sh[tid - off] : 0;
            __syncthreads();
            sh[tid] += add;
            __syncthreads();
        }
        int excl = sh[tid] - v + carry;
        if (j < B1) Bh[(size_t)j * NB + b] = excl;
        int tot = sh[255];
        __syncthreads();
        carry += tot;
    }
    if (tid == 0) total[b] = carry;
}

// ---- phase 1c: exclusive scan of bucket totals (NB <= 512), single block ----
__global__ void k_base_scan(const int* __restrict__ total, int NB, int E,
                            int* __restrict__ base) {
    __shared__ int sh[512];
    int tid = threadIdx.x;
    int v = (tid < NB) ? total[tid] : 0;
    sh[tid] = v;
    __syncthreads();
    for (int off = 1; off < 512; off <<= 1) {
        int add = (tid >= off) ? sh[tid - off] : 0;
        __syncthreads();
        sh[tid] += add;
        __syncthreads();
    }
    if (tid < NB) base[tid] = sh[tid] - v;
    if (tid == 0) base[NB] = E;
}

// ---- phase 2: LDS-binned scatter of packed records into ebuf ----
// record = (dst & 255) << 24 | src      (src < 2^17)
__global__ void k_scatter(const int* __restrict__ src, const int* __restrict__ dst,
                          int E, int NB, const int* __restrict__ Bh,
                          const int* __restrict__ base, unsigned* __restrict__ ebuf) {
    __shared__ int h[512];
    __shared__ int cur[512];
    __shared__ int gb[512];
    __shared__ int sh[256];
    __shared__ unsigned srec[CHUNK];
    __shared__ int spos[CHUNK];
    int tid = threadIdx.x;
    for (int i = tid; i < 512; i += 256) h[i] = 0;
    __syncthreads();
    int s = blockIdx.x * CHUNK;
    int e = min(s + CHUNK, E);
    for (int i = s + tid; i < e; i += 256) atomicAdd(&h[dst[i] >> SHIFT], 1);
    __syncthreads();
    int carry = 0;
    for (int part = 0; part < 2; part++) {
        int idx = part * 256 + tid;
        int v = h[idx];
        sh[tid] = v;
        __syncthreads();
        for (int off = 1; off < 256; off <<= 1) {
            int add = (tid >= off) ? sh[tid - off] : 0;
            __syncthreads();
            sh[tid] += add;
            __syncthreads();
        }
        int excl = sh[tid] - v + carry;
        int tot = sh[255];
        __syncthreads();
        h[idx] = excl;
        carry += tot;
        __syncthreads();
    }
    for (int b = tid; b < NB; b += 256) {
        cur[b] = h[b];
        gb[b]  = base[b] + Bh[(size_t)blockIdx.x * NB + b] - h[b];
    }
    __syncthreads();
    for (int i = s + tid; i < e; i += 256) {
        int d = dst[i];
        int b = d >> SHIFT;
        unsigned rec = ((unsigned)(d & 255) << 24) | (unsigned)src[i];
        int lpos = atomicAdd(&cur[b], 1);
        srec[lpos] = rec;
        spos[lpos] = gb[b] + lpos;
    }
    __syncthreads();
    int cntE = e - s;
    for (int t = tid; t < cntE; t += 256) ebuf[spos[t]] = srec[t];
}

// ---- phase 3: per-bucket counting sort -> row_ptr + col (byte offsets) ----
__global__ void k_bucket_sort(const unsigned* __restrict__ ebuf,
                              const int* __restrict__ base, int n, int E,
                              int* __restrict__ row_ptr, int* __restrict__ col) {
    __shared__ int cnt[256];
    __shared__ int sh[256];
    __shared__ int cur[256];
    __shared__ unsigned srec[BCAP];
    int b = blockIdx.x;
    int tid = threadIdx.x;
    int s = base[b];
    int e = base[b + 1];
    int len = e - s;
    cnt[tid] = 0;
    __syncthreads();
    for (int i = s + tid; i < e; i += 256) atomicAdd(&cnt[ebuf[i] >> 24], 1);
    __syncthreads();
    int c = cnt[tid];
    sh[tid] = c;
    __syncthreads();
    for (int off = 1; off < 256; off <<= 1) {
        int add = (tid >= off) ? sh[tid - off] : 0;
        __syncthreads();
        sh[tid] += add;
        __syncthreads();
    }
    int excl = sh[tid] - c;
    int node = (b << SHIFT) | tid;
    if (node < n) row_ptr[node] = s + excl;
    cur[tid] = excl;
    __syncthreads();
    if (len <= BCAP) {
        for (int i = s + tid; i < e; i += 256) {
            unsigned v = ebuf[i];
            int lpos = atomicAdd(&cur[v >> 24], 1);
            srec[lpos] = (v & 0x00FFFFFFu) << 7;   // byte offset: src * 128
        }
        __syncthreads();
        for (int t = tid; t < len; t += 256) col[s + t] = (int)srec[t];
    } else {
        for (int i = s + tid; i < e; i += 256) {
            unsigned v = ebuf[i];
            int lpos = atomicAdd(&cur[v >> 24], 1);
            col[s + lpos] = (int)((v & 0x00FFFFFFu) << 7);
        }
    }
    if (b == 0 && tid == 0) row_ptr[n] = E;
}

// ---- HS[row,:] = fp16(dinv[row] * (X[row,:] @ W)), 16 rows / 256 threads ----
__global__ void k_gemm_scale(const float* __restrict__ X, const float* __restrict__ W,
                             const int* __restrict__ row_ptr, int n,
                             __half* __restrict__ HS) {
    __shared__ float Ws[64][64];
    __shared__ float Xs[16][68];
    int tid = threadIdx.x;
    {
        const float4* W4 = (const float4*)W;
        float4* Ws4 = (float4*)&Ws[0][0];
#pragma unroll
        for (int j = 0; j < 4; j++) Ws4[tid + 256 * j] = W4[tid + 256 * j];
    }
    int row0 = blockIdx.x * 16;
    int r = tid >> 4;
    int c4 = (tid & 15) * 4;
    {
        int grow = row0 + r;
        float4 xv = make_float4(0.f, 0.f, 0.f, 0.f);
        if (grow < n) xv = *(const float4*)&X[(size_t)grow * 64 + c4];
        *(float4*)&Xs[r][c4] = xv;
    }
    __syncthreads();

    float4 acc = make_float4(0.f, 0.f, 0.f, 0.f);
#pragma unroll
    for (int k = 0; k < 64; k++) {
        float xv = Xs[r][k];
        float4 wv = *(const float4*)&Ws[k][c4];
        acc.x += xv * wv.x;
        acc.y += xv * wv.y;
        acc.z += xv * wv.z;
        acc.w += xv * wv.w;
    }
    int grow = row0 + r;
    if (grow < n) {
        float deg = 1.0f + (float)(row_ptr[grow + 1] - row_ptr[grow]);
        float dinv = rsqrtf(deg);
        __half2 h0 = __floats2half2_rn(acc.x * dinv, acc.y * dinv);
        __half2 h1 = __floats2half2_rn(acc.z * dinv, acc.w * dinv);
        uint2 pack;
        pack.x = *(const unsigned int*)&h0;
        pack.y = *(const unsigned int*)&h1;
        *(uint2*)&HS[(size_t)grow * 64 + c4] = pack;
    }
}

__device__ inline float4 cvt_h4(uint2 v) {
    float2 f0 = __half22float2(*(__half2*)&v.x);
    float2 f1 = __half22float2(*(__half2*)&v.y);
    return make_float4(f0.x, f0.y, f1.x, f1.y);
}

__device__ inline uint2 ld_row(const char* HSb, int boff, int c) {
    return *(const uint2*)(HSb + boff + (c << 3));
}

// ---- aggregation: one 16-lane group per node (4 nodes per wave) -----------
// Group walks its own row: 8 gathers in flight (main), 4-batch, then
// predicated singles (concurrent).  col[] holds byte offsets (src*128).
template <bool RELU>
__global__ void k_agg(const __half* __restrict__ HS, const int* __restrict__ row_ptr,
                      const int* __restrict__ col, const float* __restrict__ bias,
                      int n, float* __restrict__ out) {
    int gid = (int)((blockIdx.x * (unsigned)blockDim.x + threadIdx.x) >> 4);
    if (gid >= n) return;
    int c = threadIdx.x & 15;      // uint2 index within row (features 4c..4c+3)

    const char* __restrict__ HSb = (const char*)HS;

    int r0 = row_ptr[gid];
    int r1 = row_ptr[gid + 1];

    // self term
    float4 a0 = cvt_h4(*(const uint2*)(HSb + ((size_t)gid << 7) + (c << 3)));
    float4 a1 = make_float4(0.f, 0.f, 0.f, 0.f);
    float4 a2 = a1, a3 = a1;

    int e = r0;
    for (; e + 8 <= r1; e += 8) {
        int s0 = col[e + 0];
        int s1 = col[e + 1];
        int s2 = col[e + 2];
        int s3 = col[e + 3];
        int s4 = col[e + 4];
        int s5 = col[e + 5];
        int s6 = col[e + 6];
        int s7 = col[e + 7];
        uint2 v0 = ld_row(HSb, s0, c);
        uint2 v1 = ld_row(HSb, s1, c);
        uint2 v2 = ld_row(HSb, s2, c);
        uint2 v3 = ld_row(HSb, s3, c);
        uint2 v4 = ld_row(HSb, s4, c);
        uint2 v5 = ld_row(HSb, s5, c);
        uint2 v6 = ld_row(HSb, s6, c);
        uint2 v7 = ld_row(HSb, s7, c);
        float4 f0 = cvt_h4(v0), f1 = cvt_h4(v1), f2 = cvt_h4(v2), f3 = cvt_h4(v3);
        float4 f4 = cvt_h4(v4), f5 = cvt_h4(v5), f6 = cvt_h4(v6), f7 = cvt_h4(v7);
        a0.x += f0.x; a0.y += f0.y; a0.z += f0.z; a0.w += f0.w;
        a1.x += f1.x; a1.y += f1.y; a1.z += f1.z; a1.w += f1.w;
        a2.x += f2.x; a2.y += f2.y; a2.z += f2.z; a2.w += f2.w;
        a3.x += f3.x; a3.y += f3.y; a3.z += f3.z; a3.w += f3.w;
        a0.x += f4.x; a0.y += f4.y; a0.z += f4.z; a0.w += f4.w;
        a1.x += f5.x; a1.y += f5.y; a1.z += f5.z; a1.w += f5.w;
        a2.x += f6.x; a2.y += f6.y; a2.z += f6.z; a2.w += f6.w;
        a3.x += f7.x; a3.y += f7.y; a3.z += f7.z; a3.w += f7.w;
    }
    if (e + 4 <= r1) {
        int s0 = col[e + 0];
        int s1 = col[e + 1];
        int s2 = col[e + 2];
        int s3 = col[e + 3];
        uint2 v0 = ld_row(HSb, s0, c);
        uint2 v1 = ld_row(HSb, s1, c);
        uint2 v2 = ld_row(HSb, s2, c);
        uint2 v3 = ld_row(HSb, s3, c);
        float4 f0 = cvt_h4(v0), f1 = cvt_h4(v1), f2 = cvt_h4(v2), f3 = cvt_h4(v3);
        a0.x += f0.x; a0.y += f0.y; a0.z += f0.z; a0.w += f0.w;
        a1.x += f1.x; a1.y += f1.y; a1.z += f1.z; a1.w += f1.w;
        a2.x += f2.x; a2.y += f2.y; a2.z += f2.z; a2.w += f2.w;
        a3.x += f3.x; a3.y += f3.y; a3.z += f3.z; a3.w += f3.w;
        e += 4;
    }
    // predicated singles (independent -> concurrent)
    if (e + 0 < r1) {
        float4 f = cvt_h4(ld_row(HSb, col[e + 0], c));
        a0.x += f.x; a0.y += f.y; a0.z += f.z; a0.w += f.w;
    }
    if (e + 1 < r1) {
        float4 f = cvt_h4(ld_row(HSb, col[e + 1], c));
        a1.x += f.x; a1.y += f.y; a1.z += f.z; a1.w += f.w;
    }
    if (e + 2 < r1) {
        float4 f = cvt_h4(ld_row(HSb, col[e + 2], c));
        a2.x += f.x; a2.y += f.y; a2.z += f.z; a2.w += f.w;
    }

    float4 s;
    s.x = (a0.x + a1.x) + (a2.x + a3.x);
    s.y = (a0.y + a1.y) + (a2.y + a3.y);
    s.z = (a0.z + a1.z) + (a2.z + a3.z);
    s.w = (a0.w + a1.w) + (a2.w + a3.w);

    float deg = 1.0f + (float)(r1 - r0);
    float dinv = rsqrtf(deg);
    float4 bv = *(const float4*)&bias[4 * c];
    float vx = dinv * s.x + bv.x;
    float vy = dinv * s.y + bv.y;
    float vz = dinv * s.z + bv.z;
    float vw = dinv * s.w + bv.w;
    if (RELU) {
        vx = (vx >= 0.f) ? vx : 0.01f * vx;
        vy = (vy >= 0.f) ? vy : 0.01f * vy;
        vz = (vz >= 0.f) ? vz : 0.01f * vz;
        vw = (vw >= 0.f) ? vw : 0.01f * vw;
    }
    *(float4*)&out[(size_t)gid * 64 + 4 * c] = make_float4(vx, vy, vz, vw);
}

static inline size_t align256(size_t x) { return (x + 255) & ~(size_t)255; }

extern "C" void kernel_launch(void* const* d_in, const int* in_sizes, int n_in,
                              void* d_out, int out_size, void* d_ws, size_t ws_size,
                              hipStream_t stream) {
    const float* x  = (const float*)d_in[0];
    const float* W1 = (const float*)d_in[1];
    const float* b1 = (const float*)d_in[2];
    const float* W2 = (const float*)d_in[3];
    const float* b2 = (const float*)d_in[4];
    const float* W3 = (const float*)d_in[5];
    const float* b3 = (const float*)d_in[6];
    const int* edge = (const int*)d_in[7];

    int n = in_sizes[0] / 64;
    int E = in_sizes[7] / 2;
    const int* srcp = edge;
    const int* dstp = edge + E;

    int NB = (n + 255) >> SHIFT;              // buckets (391 for n=100000)
    int B1 = (E + CHUNK - 1) / CHUNK;         // histogram/scatter blocks

    char* ws = (char*)d_ws;
    int* row_ptr   = (int*)ws;      ws += align256((size_t)(n + 1) * 4);
    int* Bh        = (int*)ws;      ws += align256((size_t)B1 * NB * 4);
    int* total     = (int*)ws;      ws += align256((size_t)NB * 4);
    int* base      = (int*)ws;      ws += align256((size_t)(NB + 1) * 4);
    unsigned* ebuf = (unsigned*)ws; ws += align256((size_t)E * 4);
    int* col       = (int*)ws;      ws += align256((size_t)E * 4);
    __half* hs     = (__half*)ws;   ws += align256((size_t)n * 64 * 2);
    float* buf     = (float*)ws;    ws += align256((size_t)n * 64 * 4);
    float* out     = (float*)d_out;

    // ---- CSR build: two-level bucket sort (LDS-binned writes) ----
    k_hist<<<B1, 256, 0, stream>>>(dstp, E, NB, Bh);
    k_bucket_scan<<<NB, 256, 0, stream>>>(Bh, B1, NB, total);
    k_base_scan<<<1, 512, 0, stream>>>(total, NB, E, base);
    k_scatter<<<B1, 256, 0, stream>>>(srcp, dstp, E, NB, Bh, base, ebuf);
    k_bucket_sort<<<NB, 256, 0, stream>>>(ebuf, base, n, E, row_ptr, col);

    int gemm_blocks = (n + 15) / 16;
    int agg_blocks  = (n + 15) / 16;   // 16 nodes per 256-thread block

    // ---- layer 1: conv -> LeakyReLU ----
    k_gemm_scale<<<gemm_blocks, 256, 0, stream>>>(x, W1, row_ptr, n, hs);
    k_agg<true><<<agg_blocks, 256, 0, stream>>>(hs, row_ptr, col, b1, n, out);
    // ---- layer 2: conv ----
    k_gemm_scale<<<gemm_blocks, 256, 0, stream>>>(out, W2, row_ptr, n, hs);
    k_agg<false><<<agg_blocks, 256, 0, stream>>>(hs, row_ptr, col, b2, n, buf);
    // ---- layer 3: conv -> LeakyReLU ----
    k_gemm_scale<<<gemm_blocks, 256, 0, stream>>>(buf, W3, row_ptr, n, hs);
    k_agg<true><<<agg_blocks, 256, 0, stream>>>(hs, row_ptr, col, b3, n, out);
}

// Round 9
// 181.003 us; speedup vs baseline: 2.4704x; 1.1383x over previous
//
#include <hip/hip_runtime.h>
#include <hip/hip_fp16.h>
#include <math.h>

// ---------------------------------------------------------------------------
// GCN 3-layer forward on MI355X.
// Per layer (D=64):
//   hs[i,:] = fp16( dinv[i] * (x[i,:] @ W) )
//   out[i,:]= dinv[i] * (hs[i,:] + sum_{e: dst(e)=i} hs[src(e),:]) + b
//   optional LeakyReLU(0.01);   dinv[i] = rsqrt(1 + indeg(i))
//
// Round-9: fuse the NEXT layer's GEMM into the agg epilogue.
//   A 16-lane group holds its node's full post-activation row -> stage to LDS
//   (wave-internal ordering, no barrier) -> 64-iter scalar x float4 FMA vs
//   LDS-staged W -> scale dinv -> write fp16 hs_next.  Kills 2 GEMM kernels
//   and the 51MB fp32 out-write/read round trip per boundary.  k_agg itself
//   is at the per-CU VMEM byte-rate floor (~10.4 B/cyc/CU = m13 streaming).
// CSR build: two-level bucket sort with LDS-binned writes (rounds 4-7).
// ---------------------------------------------------------------------------

constexpr int SHIFT = 8;          // bucket = dst >> 8  (256 nodes per bucket)
constexpr int CHUNK = 4096;       // edges per phase-1/scatter block
constexpr int BCAP  = 5120;       // bucket staging capacity (mean 4096, sd 64)

// ---- phase 1: per-block bucket histogram (block-major layout Bh[j*NB+b]) ----
__global__ void k_hist(const int* __restrict__ dst, int E, int NB,
                       int* __restrict__ Bh) {
    __shared__ int h[512];
    int tid = threadIdx.x;
    for (int i = tid; i < 512; i += 256) h[i] = 0;
    __syncthreads();
    int s = blockIdx.x * CHUNK;
    int e = min(s + CHUNK, E);
    for (int i = s + tid; i < e; i += 256) atomicAdd(&h[dst[i] >> SHIFT], 1);
    __syncthreads();
    for (int i = tid; i < NB; i += 256) Bh[(size_t)blockIdx.x * NB + i] = h[i];
}

// ---- phase 1b: per-bucket exclusive scan down the block axis ----
__global__ void k_bucket_scan(int* __restrict__ Bh, int B1, int NB,
                              int* __restrict__ total) {
    __shared__ int sh[256];
    int b = blockIdx.x;
    int tid = threadIdx.x;
    int carry = 0;
    for (int j0 = 0; j0 < B1; j0 += 256) {
        int j = j0 + tid;
        int v = (j < B1) ? Bh[(size_t)j * NB + b] : 0;
        sh[tid] = v;
        __syncthreads();
        for (int off = 1; off < 256; off <<= 1) {
            int add = (tid >= off) ? sh[tid - off] : 0;
            __syncthreads();
            sh[tid] += add;
            __syncthreads();
        }
        int excl = sh[tid] - v + carry;
        if (j < B1) Bh[(size_t)j * NB + b] = excl;
        int tot = sh[255];
        __syncthreads();
        carry += tot;
    }
    if (tid == 0) total[b] = carry;
}

// ---- phase 1c: exclusive scan of bucket totals (NB <= 512), single block ----
__global__ void k_base_scan(const int* __restrict__ total, int NB, int E,
                            int* __restrict__ base) {
    __shared__ int sh[512];
    int tid = threadIdx.x;
    int v = (tid < NB) ? total[tid] : 0;
    sh[tid] = v;
    __syncthreads();
    for (int off = 1; off < 512; off <<= 1) {
        int add = (tid >= off) ? sh[tid - off] : 0;
        __syncthreads();
        sh[tid] += add;
        __syncthreads();
    }
    if (tid < NB) base[tid] = sh[tid] - v;
    if (tid == 0) base[NB] = E;
}

// ---- phase 2: LDS-binned scatter of packed records into ebuf ----
// record = (dst & 255) << 24 | src      (src < 2^17)
__global__ void k_scatter(const int* __restrict__ src, const int* __restrict__ dst,
                          int E, int NB, const int* __restrict__ Bh,
                          const int* __restrict__ base, unsigned* __restrict__ ebuf) {
    __shared__ int h[512];
    __shared__ int cur[512];
    __shared__ int gb[512];
    __shared__ int sh[256];
    __shared__ unsigned srec[CHUNK];
    __shared__ int spos[CHUNK];
    int tid = threadIdx.x;
    for (int i = tid; i < 512; i += 256) h[i] = 0;
    __syncthreads();
    int s = blockIdx.x * CHUNK;
    int e = min(s + CHUNK, E);
    for (int i = s + tid; i < e; i += 256) atomicAdd(&h[dst[i] >> SHIFT], 1);
    __syncthreads();
    int carry = 0;
    for (int part = 0; part < 2; part++) {
        int idx = part * 256 + tid;
        int v = h[idx];
        sh[tid] = v;
        __syncthreads();
        for (int off = 1; off < 256; off <<= 1) {
            int add = (tid >= off) ? sh[tid - off] : 0;
            __syncthreads();
            sh[tid] += add;
            __syncthreads();
        }
        int excl = sh[tid] - v + carry;
        int tot = sh[255];
        __syncthreads();
        h[idx] = excl;
        carry += tot;
        __syncthreads();
    }
    for (int b = tid; b < NB; b += 256) {
        cur[b] = h[b];
        gb[b]  = base[b] + Bh[(size_t)blockIdx.x * NB + b] - h[b];
    }
    __syncthreads();
    for (int i = s + tid; i < e; i += 256) {
        int d = dst[i];
        int b = d >> SHIFT;
        unsigned rec = ((unsigned)(d & 255) << 24) | (unsigned)src[i];
        int lpos = atomicAdd(&cur[b], 1);
        srec[lpos] = rec;
        spos[lpos] = gb[b] + lpos;
    }
    __syncthreads();
    int cntE = e - s;
    for (int t = tid; t < cntE; t += 256) ebuf[spos[t]] = srec[t];
}

// ---- phase 3: per-bucket counting sort -> row_ptr + col (byte offsets) ----
__global__ void k_bucket_sort(const unsigned* __restrict__ ebuf,
                              const int* __restrict__ base, int n, int E,
                              int* __restrict__ row_ptr, int* __restrict__ col) {
    __shared__ int cnt[256];
    __shared__ int sh[256];
    __shared__ int cur[256];
    __shared__ unsigned srec[BCAP];
    int b = blockIdx.x;
    int tid = threadIdx.x;
    int s = base[b];
    int e = base[b + 1];
    int len = e - s;
    cnt[tid] = 0;
    __syncthreads();
    for (int i = s + tid; i < e; i += 256) atomicAdd(&cnt[ebuf[i] >> 24], 1);
    __syncthreads();
    int c = cnt[tid];
    sh[tid] = c;
    __syncthreads();
    for (int off = 1; off < 256; off <<= 1) {
        int add = (tid >= off) ? sh[tid - off] : 0;
        __syncthreads();
        sh[tid] += add;
        __syncthreads();
    }
    int excl = sh[tid] - c;
    int node = (b << SHIFT) | tid;
    if (node < n) row_ptr[node] = s + excl;
    cur[tid] = excl;
    __syncthreads();
    if (len <= BCAP) {
        for (int i = s + tid; i < e; i += 256) {
            unsigned v = ebuf[i];
            int lpos = atomicAdd(&cur[v >> 24], 1);
            srec[lpos] = (v & 0x00FFFFFFu) << 7;   // byte offset: src * 128
        }
        __syncthreads();
        for (int t = tid; t < len; t += 256) col[s + t] = (int)srec[t];
    } else {
        for (int i = s + tid; i < e; i += 256) {
            unsigned v = ebuf[i];
            int lpos = atomicAdd(&cur[v >> 24], 1);
            col[s + lpos] = (int)((v & 0x00FFFFFFu) << 7);
        }
    }
    if (b == 0 && tid == 0) row_ptr[n] = E;
}

// ---- HS[row,:] = fp16(dinv[row] * (X[row,:] @ W)), 16 rows / 256 threads ----
__global__ void k_gemm_scale(const float* __restrict__ X, const float* __restrict__ W,
                             const int* __restrict__ row_ptr, int n,
                             __half* __restrict__ HS) {
    __shared__ float Ws[64][64];
    __shared__ float Xs[16][68];
    int tid = threadIdx.x;
    {
        const float4* W4 = (const float4*)W;
        float4* Ws4 = (float4*)&Ws[0][0];
#pragma unroll
        for (int j = 0; j < 4; j++) Ws4[tid + 256 * j] = W4[tid + 256 * j];
    }
    int row0 = blockIdx.x * 16;
    int r = tid >> 4;
    int c4 = (tid & 15) * 4;
    {
        int grow = row0 + r;
        float4 xv = make_float4(0.f, 0.f, 0.f, 0.f);
        if (grow < n) xv = *(const float4*)&X[(size_t)grow * 64 + c4];
        *(float4*)&Xs[r][c4] = xv;
    }
    __syncthreads();

    float4 acc = make_float4(0.f, 0.f, 0.f, 0.f);
#pragma unroll
    for (int k = 0; k < 64; k++) {
        float xv = Xs[r][k];
        float4 wv = *(const float4*)&Ws[k][c4];
        acc.x += xv * wv.x;
        acc.y += xv * wv.y;
        acc.z += xv * wv.z;
        acc.w += xv * wv.w;
    }
    int grow = row0 + r;
    if (grow < n) {
        float deg = 1.0f + (float)(row_ptr[grow + 1] - row_ptr[grow]);
        float dinv = rsqrtf(deg);
        __half2 h0 = __floats2half2_rn(acc.x * dinv, acc.y * dinv);
        __half2 h1 = __floats2half2_rn(acc.z * dinv, acc.w * dinv);
        uint2 pack;
        pack.x = *(const unsigned int*)&h0;
        pack.y = *(const unsigned int*)&h1;
        *(uint2*)&HS[(size_t)grow * 64 + c4] = pack;
    }
}

__device__ inline float4 cvt_h4(uint2 v) {
    float2 f0 = __half22float2(*(__half2*)&v.x);
    float2 f1 = __half22float2(*(__half2*)&v.y);
    return make_float4(f0.x, f0.y, f1.x, f1.y);
}

__device__ inline uint2 ld_row(const char* HSb, int boff, int c) {
    return *(const uint2*)(HSb + boff + (c << 3));
}

// Gather-aggregate one node's row: s = hs[self] + sum hs[src].  16-lane
// group, 8 gathers in flight (main), 4-batch, predicated singles.
__device__ inline float4 agg_row(const char* __restrict__ HSb,
                                 const int* __restrict__ col,
                                 int gid, int c, int r0, int r1) {
    float4 a0 = cvt_h4(*(const uint2*)(HSb + ((size_t)gid << 7) + (c << 3)));
    float4 a1 = make_float4(0.f, 0.f, 0.f, 0.f);
    float4 a2 = a1, a3 = a1;
    int e = r0;
    for (; e + 8 <= r1; e += 8) {
        int s0 = col[e + 0], s1 = col[e + 1], s2 = col[e + 2], s3 = col[e + 3];
        int s4 = col[e + 4], s5 = col[e + 5], s6 = col[e + 6], s7 = col[e + 7];
        uint2 v0 = ld_row(HSb, s0, c), v1 = ld_row(HSb, s1, c);
        uint2 v2 = ld_row(HSb, s2, c), v3 = ld_row(HSb, s3, c);
        uint2 v4 = ld_row(HSb, s4, c), v5 = ld_row(HSb, s5, c);
        uint2 v6 = ld_row(HSb, s6, c), v7 = ld_row(HSb, s7, c);
        float4 f0 = cvt_h4(v0), f1 = cvt_h4(v1), f2 = cvt_h4(v2), f3 = cvt_h4(v3);
        float4 f4 = cvt_h4(v4), f5 = cvt_h4(v5), f6 = cvt_h4(v6), f7 = cvt_h4(v7);
        a0.x += f0.x; a0.y += f0.y; a0.z += f0.z; a0.w += f0.w;
        a1.x += f1.x; a1.y += f1.y; a1.z += f1.z; a1.w += f1.w;
        a2.x += f2.x; a2.y += f2.y; a2.z += f2.z; a2.w += f2.w;
        a3.x += f3.x; a3.y += f3.y; a3.z += f3.z; a3.w += f3.w;
        a0.x += f4.x; a0.y += f4.y; a0.z += f4.z; a0.w += f4.w;
        a1.x += f5.x; a1.y += f5.y; a1.z += f5.z; a1.w += f5.w;
        a2.x += f6.x; a2.y += f6.y; a2.z += f6.z; a2.w += f6.w;
        a3.x += f7.x; a3.y += f7.y; a3.z += f7.z; a3.w += f7.w;
    }
    if (e + 4 <= r1) {
        int s0 = col[e + 0], s1 = col[e + 1], s2 = col[e + 2], s3 = col[e + 3];
        uint2 v0 = ld_row(HSb, s0, c), v1 = ld_row(HSb, s1, c);
        uint2 v2 = ld_row(HSb, s2, c), v3 = ld_row(HSb, s3, c);
        float4 f0 = cvt_h4(v0), f1 = cvt_h4(v1), f2 = cvt_h4(v2), f3 = cvt_h4(v3);
        a0.x += f0.x; a0.y += f0.y; a0.z += f0.z; a0.w += f0.w;
        a1.x += f1.x; a1.y += f1.y; a1.z += f1.z; a1.w += f1.w;
        a2.x += f2.x; a2.y += f2.y; a2.z += f2.z; a2.w += f2.w;
        a3.x += f3.x; a3.y += f3.y; a3.z += f3.z; a3.w += f3.w;
        e += 4;
    }
    if (e + 0 < r1) {
        float4 f = cvt_h4(ld_row(HSb, col[e + 0], c));
        a0.x += f.x; a0.y += f.y; a0.z += f.z; a0.w += f.w;
    }
    if (e + 1 < r1) {
        float4 f = cvt_h4(ld_row(HSb, col[e + 1], c));
        a1.x += f.x; a1.y += f.y; a1.z += f.z; a1.w += f.w;
    }
    if (e + 2 < r1) {
        float4 f = cvt_h4(ld_row(HSb, col[e + 2], c));
        a2.x += f.x; a2.y += f.y; a2.z += f.z; a2.w += f.w;
    }
    float4 s;
    s.x = (a0.x + a1.x) + (a2.x + a3.x);
    s.y = (a0.y + a1.y) + (a2.y + a3.y);
    s.z = (a0.z + a1.z) + (a2.z + a3.z);
    s.w = (a0.w + a1.w) + (a2.w + a3.w);
    return s;
}

// ---- fused: agg epilogue + next-layer GEMM -> fp16 hs_next ----------------
// v = act(dinv*s + b);  hs_next[i] = fp16(dinv[i] * (v @ Wn))
template <bool RELU>
__global__ void k_agg_gemm(const __half* __restrict__ HS, const int* __restrict__ row_ptr,
                           const int* __restrict__ col, const float* __restrict__ bias,
                           const float* __restrict__ Wn, int n,
                           __half* __restrict__ HSn) {
    __shared__ float Wl[64][64];    // 16 KB
    __shared__ float rows[16][68];  // padded
    int tid = threadIdx.x;
    {
        const float4* W4 = (const float4*)Wn;
        float4* Wl4 = (float4*)&Wl[0][0];
#pragma unroll
        for (int j = 0; j < 4; j++) Wl4[tid + 256 * j] = W4[tid + 256 * j];
    }
    __syncthreads();   // Wl ready for all waves; no barriers after this

    int gid = blockIdx.x * 16 + (tid >> 4);
    if (gid >= n) return;
    int g = tid >> 4;
    int c = tid & 15;

    const char* __restrict__ HSb = (const char*)HS;
    int r0 = row_ptr[gid];
    int r1 = row_ptr[gid + 1];

    float4 s = agg_row(HSb, col, gid, c, r0, r1);

    float deg = 1.0f + (float)(r1 - r0);
    float dinv = rsqrtf(deg);
    float4 bv = *(const float4*)&bias[4 * c];
    float vx = dinv * s.x + bv.x;
    float vy = dinv * s.y + bv.y;
    float vz = dinv * s.z + bv.z;
    float vw = dinv * s.w + bv.w;
    if (RELU) {
        vx = (vx >= 0.f) ? vx : 0.01f * vx;
        vy = (vy >= 0.f) ? vy : 0.01f * vy;
        vz = (vz >= 0.f) ? vz : 0.01f * vz;
        vw = (vw >= 0.f) ? vw : 0.01f * vw;
    }
    // stage row in LDS; written and read only by this 16-lane group (same
    // wave) -> wave-internal LDS ordering, no block barrier needed.
    *(float4*)&rows[g][4 * c] = make_float4(vx, vy, vz, vw);

    float4 acc = make_float4(0.f, 0.f, 0.f, 0.f);
#pragma unroll
    for (int k = 0; k < 64; k++) {
        float xv = rows[g][k];
        float4 wv = *(const float4*)&Wl[k][4 * c];
        acc.x += xv * wv.x;
        acc.y += xv * wv.y;
        acc.z += xv * wv.z;
        acc.w += xv * wv.w;
    }
    __half2 h0 = __floats2half2_rn(acc.x * dinv, acc.y * dinv);
    __half2 h1 = __floats2half2_rn(acc.z * dinv, acc.w * dinv);
    uint2 pack;
    pack.x = *(const unsigned int*)&h0;
    pack.y = *(const unsigned int*)&h1;
    *(uint2*)&HSn[(size_t)gid * 64 + 4 * c] = pack;
}

// ---- final layer: agg + bias + LeakyReLU -> fp32 out ----------------------
__global__ void k_agg_out(const __half* __restrict__ HS, const int* __restrict__ row_ptr,
                          const int* __restrict__ col, const float* __restrict__ bias,
                          int n, float* __restrict__ out) {
    int gid = (int)((blockIdx.x * (unsigned)blockDim.x + threadIdx.x) >> 4);
    if (gid >= n) return;
    int c = threadIdx.x & 15;
    const char* __restrict__ HSb = (const char*)HS;
    int r0 = row_ptr[gid];
    int r1 = row_ptr[gid + 1];
    float4 s = agg_row(HSb, col, gid, c, r0, r1);
    float deg = 1.0f + (float)(r1 - r0);
    float dinv = rsqrtf(deg);
    float4 bv = *(const float4*)&bias[4 * c];
    float vx = dinv * s.x + bv.x;
    float vy = dinv * s.y + bv.y;
    float vz = dinv * s.z + bv.z;
    float vw = dinv * s.w + bv.w;
    vx = (vx >= 0.f) ? vx : 0.01f * vx;
    vy = (vy >= 0.f) ? vy : 0.01f * vy;
    vz = (vz >= 0.f) ? vz : 0.01f * vz;
    vw = (vw >= 0.f) ? vw : 0.01f * vw;
    *(float4*)&out[(size_t)gid * 64 + 4 * c] = make_float4(vx, vy, vz, vw);
}

static inline size_t align256(size_t x) { return (x + 255) & ~(size_t)255; }

extern "C" void kernel_launch(void* const* d_in, const int* in_sizes, int n_in,
                              void* d_out, int out_size, void* d_ws, size_t ws_size,
                              hipStream_t stream) {
    const float* x  = (const float*)d_in[0];
    const float* W1 = (const float*)d_in[1];
    const float* b1 = (const float*)d_in[2];
    const float* W2 = (const float*)d_in[3];
    const float* b2 = (const float*)d_in[4];
    const float* W3 = (const float*)d_in[5];
    const float* b3 = (const float*)d_in[6];
    const int* edge = (const int*)d_in[7];

    int n = in_sizes[0] / 64;
    int E = in_sizes[7] / 2;
    const int* srcp = edge;
    const int* dstp = edge + E;

    int NB = (n + 255) >> SHIFT;              // buckets (391 for n=100000)
    int B1 = (E + CHUNK - 1) / CHUNK;         // histogram/scatter blocks

    char* ws = (char*)d_ws;
    int* row_ptr   = (int*)ws;      ws += align256((size_t)(n + 1) * 4);
    int* Bh        = (int*)ws;      ws += align256((size_t)B1 * NB * 4);
    int* total     = (int*)ws;      ws += align256((size_t)NB * 4);
    int* base      = (int*)ws;      ws += align256((size_t)(NB + 1) * 4);
    unsigned* ebuf = (unsigned*)ws; ws += align256((size_t)E * 4);
    int* col       = (int*)ws;      ws += align256((size_t)E * 4);
    __half* hs_a   = (__half*)ws;   ws += align256((size_t)n * 64 * 2);
    __half* hs_b   = (__half*)ws;   ws += align256((size_t)n * 64 * 2);
    float* out     = (float*)d_out;

    // ---- CSR build: two-level bucket sort (LDS-binned writes) ----
    k_hist<<<B1, 256, 0, stream>>>(dstp, E, NB, Bh);
    k_bucket_scan<<<NB, 256, 0, stream>>>(Bh, B1, NB, total);
    k_base_scan<<<1, 512, 0, stream>>>(total, NB, E, base);
    k_scatter<<<B1, 256, 0, stream>>>(srcp, dstp, E, NB, Bh, base, ebuf);
    k_bucket_sort<<<NB, 256, 0, stream>>>(ebuf, base, n, E, row_ptr, col);

    int blocks16 = (n + 15) / 16;   // 16 nodes per 256-thread block

    // layer 1 GEMM: hs_a = fp16(dinv * (x @ W1))
    k_gemm_scale<<<blocks16, 256, 0, stream>>>(x, W1, row_ptr, n, hs_a);
    // layer 1 agg (+relu) fused with layer 2 GEMM: hs_b
    k_agg_gemm<true><<<blocks16, 256, 0, stream>>>(hs_a, row_ptr, col, b1, W2, n, hs_b);
    // layer 2 agg (no act) fused with layer 3 GEMM: hs_a
    k_agg_gemm<false><<<blocks16, 256, 0, stream>>>(hs_b, row_ptr, col, b2, W3, n, hs_a);
    // layer 3 agg + bias + relu -> out
    k_agg_out<<<blocks16, 256, 0, stream>>>(hs_a, row_ptr, col, b3, n, out);
}

// Round 10
// 170.674 us; speedup vs baseline: 2.6199x; 1.0605x over previous
//
#include <hip/hip_runtime.h>
#include <hip/hip_fp16.h>
#include <math.h>

// ---------------------------------------------------------------------------
// GCN 3-layer forward on MI355X.
// Per layer (D=64):
//   hs[i,:] = fp16( dinv[i] * (x[i,:] @ W) )
//   out[i,:]= dinv[i] * (hs[i,:] + sum_{e: dst(e)=i} hs[src(e),:]) + b
//   optional LeakyReLU(0.01);   dinv[i] = rsqrt(1 + indeg(i))
//
// Round-10: fused agg+GEMM now uses MFMA for the GEMM phase.
//   r9's scalar FMA loop was LDS-pipe-bound (64 b128 + 64 b32 per wave ~1140
//   cyc -> the GEMM added ~11us serially).  Now: rows (16x64 fp16) @ W(fp16,
//   transposed in LDS) via mfma_f32_16x16x32_f16 -- per wave 4 ds_read_b128
//   + 2 MFMA.  One barrier between agg and MFMA phases.  LDS 21KB -> 11.6KB.
// k_agg gather structure (r8) is at the per-CU VMEM request floor; CSR build
// (r4-r7) via two-level bucket sort with LDS-binned writes.
// ---------------------------------------------------------------------------

constexpr int SHIFT = 8;          // bucket = dst >> 8  (256 nodes per bucket)
constexpr int CHUNK = 4096;       // edges per phase-1/scatter block
constexpr int BCAP  = 5120;       // bucket staging capacity (mean 4096, sd 64)

typedef _Float16 half8 __attribute__((ext_vector_type(8)));
typedef float floatx4 __attribute__((ext_vector_type(4)));

// ---- phase 1: per-block bucket histogram (block-major layout Bh[j*NB+b]) ----
__global__ void k_hist(const int* __restrict__ dst, int E, int NB,
                       int* __restrict__ Bh) {
    __shared__ int h[512];
    int tid = threadIdx.x;
    for (int i = tid; i < 512; i += 256) h[i] = 0;
    __syncthreads();
    int s = blockIdx.x * CHUNK;
    int e = min(s + CHUNK, E);
    for (int i = s + tid; i < e; i += 256) atomicAdd(&h[dst[i] >> SHIFT], 1);
    __syncthreads();
    for (int i = tid; i < NB; i += 256) Bh[(size_t)blockIdx.x * NB + i] = h[i];
}

// ---- phase 1b: per-bucket exclusive scan down the block axis ----
__global__ void k_bucket_scan(int* __restrict__ Bh, int B1, int NB,
                              int* __restrict__ total) {
    __shared__ int sh[256];
    int b = blockIdx.x;
    int tid = threadIdx.x;
    int carry = 0;
    for (int j0 = 0; j0 < B1; j0 += 256) {
        int j = j0 + tid;
        int v = (j < B1) ? Bh[(size_t)j * NB + b] : 0;
        sh[tid] = v;
        __syncthreads();
        for (int off = 1; off < 256; off <<= 1) {
            int add = (tid >= off) ? sh[tid - off] : 0;
            __syncthreads();
            sh[tid] += add;
            __syncthreads();
        }
        int excl = sh[tid] - v + carry;
        if (j < B1) Bh[(size_t)j * NB + b] = excl;
        int tot = sh[255];
        __syncthreads();
        carry += tot;
    }
    if (tid == 0) total[b] = carry;
}

// ---- phase 1c: exclusive scan of bucket totals (NB <= 512), single block ----
__global__ void k_base_scan(const int* __restrict__ total, int NB, int E,
                            int* __restrict__ base) {
    __shared__ int sh[512];
    int tid = threadIdx.x;
    int v = (tid < NB) ? total[tid] : 0;
    sh[tid] = v;
    __syncthreads();
    for (int off = 1; off < 512; off <<= 1) {
        int add = (tid >= off) ? sh[tid - off] : 0;
        __syncthreads();
        sh[tid] += add;
        __syncthreads();
    }
    if (tid < NB) base[tid] = sh[tid] - v;
    if (tid == 0) base[NB] = E;
}

// ---- phase 2: LDS-binned scatter of packed records into ebuf ----
// record = (dst & 255) << 24 | src      (src < 2^17)
__global__ void k_scatter(const int* __restrict__ src, const int* __restrict__ dst,
                          int E, int NB, const int* __restrict__ Bh,
                          const int* __restrict__ base, unsigned* __restrict__ ebuf) {
    __shared__ int h[512];
    __shared__ int cur[512];
    __shared__ int gb[512];
    __shared__ int sh[256];
    __shared__ unsigned srec[CHUNK];
    __shared__ int spos[CHUNK];
    int tid = threadIdx.x;
    for (int i = tid; i < 512; i += 256) h[i] = 0;
    __syncthreads();
    int s = blockIdx.x * CHUNK;
    int e = min(s + CHUNK, E);
    for (int i = s + tid; i < e; i += 256) atomicAdd(&h[dst[i] >> SHIFT], 1);
    __syncthreads();
    int carry = 0;
    for (int part = 0; part < 2; part++) {
        int idx = part * 256 + tid;
        int v = h[idx];
        sh[tid] = v;
        __syncthreads();
        for (int off = 1; off < 256; off <<= 1) {
            int add = (tid >= off) ? sh[tid - off] : 0;
            __syncthreads();
            sh[tid] += add;
            __syncthreads();
        }
        int excl = sh[tid] - v + carry;
        int tot = sh[255];
        __syncthreads();
        h[idx] = excl;
        carry += tot;
        __syncthreads();
    }
    for (int b = tid; b < NB; b += 256) {
        cur[b] = h[b];
        gb[b]  = base[b] + Bh[(size_t)blockIdx.x * NB + b] - h[b];
    }
    __syncthreads();
    for (int i = s + tid; i < e; i += 256) {
        int d = dst[i];
        int b = d >> SHIFT;
        unsigned rec = ((unsigned)(d & 255) << 24) | (unsigned)src[i];
        int lpos = atomicAdd(&cur[b], 1);
        srec[lpos] = rec;
        spos[lpos] = gb[b] + lpos;
    }
    __syncthreads();
    int cntE = e - s;
    for (int t = tid; t < cntE; t += 256) ebuf[spos[t]] = srec[t];
}

// ---- phase 3: per-bucket counting sort -> row_ptr + col (byte offsets) ----
__global__ void k_bucket_sort(const unsigned* __restrict__ ebuf,
                              const int* __restrict__ base, int n, int E,
                              int* __restrict__ row_ptr, int* __restrict__ col) {
    __shared__ int cnt[256];
    __shared__ int sh[256];
    __shared__ int cur[256];
    __shared__ unsigned srec[BCAP];
    int b = blockIdx.x;
    int tid = threadIdx.x;
    int s = base[b];
    int e = base[b + 1];
    int len = e - s;
    cnt[tid] = 0;
    __syncthreads();
    for (int i = s + tid; i < e; i += 256) atomicAdd(&cnt[ebuf[i] >> 24], 1);
    __syncthreads();
    int c = cnt[tid];
    sh[tid] = c;
    __syncthreads();
    for (int off = 1; off < 256; off <<= 1) {
        int add = (tid >= off) ? sh[tid - off] : 0;
        __syncthreads();
        sh[tid] += add;
        __syncthreads();
    }
    int excl = sh[tid] - c;
    int node = (b << SHIFT) | tid;
    if (node < n) row_ptr[node] = s + excl;
    cur[tid] = excl;
    __syncthreads();
    if (len <= BCAP) {
        for (int i = s + tid; i < e; i += 256) {
            unsigned v = ebuf[i];
            int lpos = atomicAdd(&cur[v >> 24], 1);
            srec[lpos] = (v & 0x00FFFFFFu) << 7;   // byte offset: src * 128
        }
        __syncthreads();
        for (int t = tid; t < len; t += 256) col[s + t] = (int)srec[t];
    } else {
        for (int i = s + tid; i < e; i += 256) {
            unsigned v = ebuf[i];
            int lpos = atomicAdd(&cur[v >> 24], 1);
            col[s + lpos] = (int)((v & 0x00FFFFFFu) << 7);
        }
    }
    if (b == 0 && tid == 0) row_ptr[n] = E;
}

// ---- HS[row,:] = fp16(dinv[row] * (X[row,:] @ W)), 16 rows / 256 threads ----
__global__ void k_gemm_scale(const float* __restrict__ X, const float* __restrict__ W,
                             const int* __restrict__ row_ptr, int n,
                             __half* __restrict__ HS) {
    __shared__ float Ws[64][64];
    __shared__ float Xs[16][68];
    int tid = threadIdx.x;
    {
        const float4* W4 = (const float4*)W;
        float4* Ws4 = (float4*)&Ws[0][0];
#pragma unroll
        for (int j = 0; j < 4; j++) Ws4[tid + 256 * j] = W4[tid + 256 * j];
    }
    int row0 = blockIdx.x * 16;
    int r = tid >> 4;
    int c4 = (tid & 15) * 4;
    {
        int grow = row0 + r;
        float4 xv = make_float4(0.f, 0.f, 0.f, 0.f);
        if (grow < n) xv = *(const float4*)&X[(size_t)grow * 64 + c4];
        *(float4*)&Xs[r][c4] = xv;
    }
    __syncthreads();

    float4 acc = make_float4(0.f, 0.f, 0.f, 0.f);
#pragma unroll
    for (int k = 0; k < 64; k++) {
        float xv = Xs[r][k];
        float4 wv = *(const float4*)&Ws[k][c4];
        acc.x += xv * wv.x;
        acc.y += xv * wv.y;
        acc.z += xv * wv.z;
        acc.w += xv * wv.w;
    }
    int grow = row0 + r;
    if (grow < n) {
        float deg = 1.0f + (float)(row_ptr[grow + 1] - row_ptr[grow]);
        float dinv = rsqrtf(deg);
        __half2 h0 = __floats2half2_rn(acc.x * dinv, acc.y * dinv);
        __half2 h1 = __floats2half2_rn(acc.z * dinv, acc.w * dinv);
        uint2 pack;
        pack.x = *(const unsigned int*)&h0;
        pack.y = *(const unsigned int*)&h1;
        *(uint2*)&HS[(size_t)grow * 64 + c4] = pack;
    }
}

__device__ inline float4 cvt_h4(uint2 v) {
    float2 f0 = __half22float2(*(__half2*)&v.x);
    float2 f1 = __half22float2(*(__half2*)&v.y);
    return make_float4(f0.x, f0.y, f1.x, f1.y);
}

__device__ inline uint2 ld_row(const char* HSb, int boff, int c) {
    return *(const uint2*)(HSb + boff + (c << 3));
}

// Gather-aggregate one node's row: s = hs[self] + sum hs[src].  16-lane
// group, 8 gathers in flight (main), 4-batch, predicated singles.
__device__ inline float4 agg_row(const char* __restrict__ HSb,
                                 const int* __restrict__ col,
                                 int gid, int c, int r0, int r1) {
    float4 a0 = cvt_h4(*(const uint2*)(HSb + ((size_t)gid << 7) + (c << 3)));
    float4 a1 = make_float4(0.f, 0.f, 0.f, 0.f);
    float4 a2 = a1, a3 = a1;
    int e = r0;
    for (; e + 8 <= r1; e += 8) {
        int s0 = col[e + 0], s1 = col[e + 1], s2 = col[e + 2], s3 = col[e + 3];
        int s4 = col[e + 4], s5 = col[e + 5], s6 = col[e + 6], s7 = col[e + 7];
        uint2 v0 = ld_row(HSb, s0, c), v1 = ld_row(HSb, s1, c);
        uint2 v2 = ld_row(HSb, s2, c), v3 = ld_row(HSb, s3, c);
        uint2 v4 = ld_row(HSb, s4, c), v5 = ld_row(HSb, s5, c);
        uint2 v6 = ld_row(HSb, s6, c), v7 = ld_row(HSb, s7, c);
        float4 f0 = cvt_h4(v0), f1 = cvt_h4(v1), f2 = cvt_h4(v2), f3 = cvt_h4(v3);
        float4 f4 = cvt_h4(v4), f5 = cvt_h4(v5), f6 = cvt_h4(v6), f7 = cvt_h4(v7);
        a0.x += f0.x; a0.y += f0.y; a0.z += f0.z; a0.w += f0.w;
        a1.x += f1.x; a1.y += f1.y; a1.z += f1.z; a1.w += f1.w;
        a2.x += f2.x; a2.y += f2.y; a2.z += f2.z; a2.w += f2.w;
        a3.x += f3.x; a3.y += f3.y; a3.z += f3.z; a3.w += f3.w;
        a0.x += f4.x; a0.y += f4.y; a0.z += f4.z; a0.w += f4.w;
        a1.x += f5.x; a1.y += f5.y; a1.z += f5.z; a1.w += f5.w;
        a2.x += f6.x; a2.y += f6.y; a2.z += f6.z; a2.w += f6.w;
        a3.x += f7.x; a3.y += f7.y; a3.z += f7.z; a3.w += f7.w;
    }
    if (e + 4 <= r1) {
        int s0 = col[e + 0], s1 = col[e + 1], s2 = col[e + 2], s3 = col[e + 3];
        uint2 v0 = ld_row(HSb, s0, c), v1 = ld_row(HSb, s1, c);
        uint2 v2 = ld_row(HSb, s2, c), v3 = ld_row(HSb, s3, c);
        float4 f0 = cvt_h4(v0), f1 = cvt_h4(v1), f2 = cvt_h4(v2), f3 = cvt_h4(v3);
        a0.x += f0.x; a0.y += f0.y; a0.z += f0.z; a0.w += f0.w;
        a1.x += f1.x; a1.y += f1.y; a1.z += f1.z; a1.w += f1.w;
        a2.x += f2.x; a2.y += f2.y; a2.z += f2.z; a2.w += f2.w;
        a3.x += f3.x; a3.y += f3.y; a3.z += f3.z; a3.w += f3.w;
        e += 4;
    }
    if (e + 0 < r1) {
        float4 f = cvt_h4(ld_row(HSb, col[e + 0], c));
        a0.x += f.x; a0.y += f.y; a0.z += f.z; a0.w += f.w;
    }
    if (e + 1 < r1) {
        float4 f = cvt_h4(ld_row(HSb, col[e + 1], c));
        a1.x += f.x; a1.y += f.y; a1.z += f.z; a1.w += f.w;
    }
    if (e + 2 < r1) {
        float4 f = cvt_h4(ld_row(HSb, col[e + 2], c));
        a2.x += f.x; a2.y += f.y; a2.z += f.z; a2.w += f.w;
    }
    float4 s;
    s.x = (a0.x + a1.x) + (a2.x + a3.x);
    s.y = (a0.y + a1.y) + (a2.y + a3.y);
    s.z = (a0.z + a1.z) + (a2.z + a3.z);
    s.w = (a0.w + a1.w) + (a2.w + a3.w);
    return s;
}

// ---- fused: agg epilogue + next-layer GEMM (MFMA) -> fp16 hs_next ---------
// v = act(dinv*s + b);  hs_next[i] = fp16(dinv[i] * (v @ Wn))
// Phase A (per 16-lane group): gather-agg, activation, stage fp16 row in LDS.
// Phase B (per wave, after barrier): 16x64 @ 64x64 fp16 MFMA; wave w computes
// columns [16w,16w+16): 2x mfma_f32_16x16x32_f16, frags straight from LDS.
template <bool RELU>
__global__ void k_agg_gemm(const __half* __restrict__ HS, const int* __restrict__ row_ptr,
                           const int* __restrict__ col, const float* __restrict__ bias,
                           const float* __restrict__ Wn, int n,
                           __half* __restrict__ HSn) {
    __shared__ _Float16 WtS[64 * 72];   // W^T, padded stride 72 (9.2 KB)
    __shared__ _Float16 rowS[16 * 72];  // staged activation rows (2.3 KB)
    __shared__ float dinvS[16];
    int tid = threadIdx.x;

    // stage W^T as fp16: thread reads W[row][col0..col0+3] coalesced,
    // scatters 4 halves into WtS[col][row].
    {
        const float4* W4 = (const float4*)Wn;
#pragma unroll
        for (int j = 0; j < 4; j++) {
            int idx = tid + 256 * j;
            int row = idx >> 4;
            int col0 = (idx & 15) * 4;
            float4 wv = W4[idx];
            WtS[(col0 + 0) * 72 + row] = (_Float16)wv.x;
            WtS[(col0 + 1) * 72 + row] = (_Float16)wv.y;
            WtS[(col0 + 2) * 72 + row] = (_Float16)wv.z;
            WtS[(col0 + 3) * 72 + row] = (_Float16)wv.w;
        }
    }

    int g = tid >> 4;             // node slot within block
    int c = tid & 15;
    int gid = blockIdx.x * 16 + g;
    bool valid = gid < n;

    float dinv = 1.0f;
    if (valid) {
        const char* __restrict__ HSb = (const char*)HS;
        int r0 = row_ptr[gid];
        int r1 = row_ptr[gid + 1];
        float4 s = agg_row(HSb, col, gid, c, r0, r1);
        float deg = 1.0f + (float)(r1 - r0);
        dinv = rsqrtf(deg);
        float4 bv = *(const float4*)&bias[4 * c];
        float vx = dinv * s.x + bv.x;
        float vy = dinv * s.y + bv.y;
        float vz = dinv * s.z + bv.z;
        float vw = dinv * s.w + bv.w;
        if (RELU) {
            vx = (vx >= 0.f) ? vx : 0.01f * vx;
            vy = (vy >= 0.f) ? vy : 0.01f * vy;
            vz = (vz >= 0.f) ? vz : 0.01f * vz;
            vw = (vw >= 0.f) ? vw : 0.01f * vw;
        }
        __half2 h0 = __floats2half2_rn(vx, vy);
        __half2 h1 = __floats2half2_rn(vz, vw);
        uint2 pack;
        pack.x = *(const unsigned int*)&h0;
        pack.y = *(const unsigned int*)&h1;
        *(uint2*)&rowS[g * 72 + c * 4] = pack;
        if (c == 0) dinvS[g] = dinv;
    }
    __syncthreads();

    // MFMA phase: wave w -> output cols [16w, 16w+16)
    int w = tid >> 6;
    int lane = tid & 63;
    int ar = lane & 15;           // A row / B col within tile
    int ks = lane >> 4;           // k-slice selector

    half8 a1 = *(const half8*)&rowS[ar * 72 + ks * 8];
    half8 a2 = *(const half8*)&rowS[ar * 72 + 32 + ks * 8];
    half8 b1 = *(const half8*)&WtS[(w * 16 + ar) * 72 + ks * 8];
    half8 b2 = *(const half8*)&WtS[(w * 16 + ar) * 72 + 32 + ks * 8];

    floatx4 acc = {0.f, 0.f, 0.f, 0.f};
    acc = __builtin_amdgcn_mfma_f32_16x16x32_f16(a1, b1, acc, 0, 0, 0);
    acc = __builtin_amdgcn_mfma_f32_16x16x32_f16(a2, b2, acc, 0, 0, 0);

    int node0 = (lane >> 4) * 4;  // C row = node0 + reg
    float4 dv4 = *(const float4*)&dinvS[node0];
    int colg = w * 16 + (lane & 15);
    int base_node = blockIdx.x * 16 + node0;
#pragma unroll
    for (int reg = 0; reg < 4; reg++) {
        int node_g = base_node + reg;
        if (node_g < n) {
            float dv = (reg == 0) ? dv4.x : (reg == 1) ? dv4.y : (reg == 2) ? dv4.z : dv4.w;
            HSn[(size_t)node_g * 64 + colg] = __float2half(acc[reg] * dv);
        }
    }
}

// ---- final layer: agg + bias + LeakyReLU -> fp32 out ----------------------
__global__ void k_agg_out(const __half* __restrict__ HS, const int* __restrict__ row_ptr,
                          const int* __restrict__ col, const float* __restrict__ bias,
                          int n, float* __restrict__ out) {
    int gid = (int)((blockIdx.x * (unsigned)blockDim.x + threadIdx.x) >> 4);
    if (gid >= n) return;
    int c = threadIdx.x & 15;
    const char* __restrict__ HSb = (const char*)HS;
    int r0 = row_ptr[gid];
    int r1 = row_ptr[gid + 1];
    float4 s = agg_row(HSb, col, gid, c, r0, r1);
    float deg = 1.0f + (float)(r1 - r0);
    float dinv = rsqrtf(deg);
    float4 bv = *(const float4*)&bias[4 * c];
    float vx = dinv * s.x + bv.x;
    float vy = dinv * s.y + bv.y;
    float vz = dinv * s.z + bv.z;
    float vw = dinv * s.w + bv.w;
    vx = (vx >= 0.f) ? vx : 0.01f * vx;
    vy = (vy >= 0.f) ? vy : 0.01f * vy;
    vz = (vz >= 0.f) ? vz : 0.01f * vz;
    vw = (vw >= 0.f) ? vw : 0.01f * vw;
    *(float4*)&out[(size_t)gid * 64 + 4 * c] = make_float4(vx, vy, vz, vw);
}

static inline size_t align256(size_t x) { return (x + 255) & ~(size_t)255; }

extern "C" void kernel_launch(void* const* d_in, const int* in_sizes, int n_in,
                              void* d_out, int out_size, void* d_ws, size_t ws_size,
                              hipStream_t stream) {
    const float* x  = (const float*)d_in[0];
    const float* W1 = (const float*)d_in[1];
    const float* b1 = (const float*)d_in[2];
    const float* W2 = (const float*)d_in[3];
    const float* b2 = (const float*)d_in[4];
    const float* W3 = (const float*)d_in[5];
    const float* b3 = (const float*)d_in[6];
    const int* edge = (const int*)d_in[7];

    int n = in_sizes[0] / 64;
    int E = in_sizes[7] / 2;
    const int* srcp = edge;
    const int* dstp = edge + E;

    int NB = (n + 255) >> SHIFT;              // buckets (391 for n=100000)
    int B1 = (E + CHUNK - 1) / CHUNK;         // histogram/scatter blocks

    char* ws = (char*)d_ws;
    int* row_ptr   = (int*)ws;      ws += align256((size_t)(n + 1) * 4);
    int* Bh        = (int*)ws;      ws += align256((size_t)B1 * NB * 4);
    int* total     = (int*)ws;      ws += align256((size_t)NB * 4);
    int* base      = (int*)ws;      ws += align256((size_t)(NB + 1) * 4);
    unsigned* ebuf = (unsigned*)ws; ws += align256((size_t)E * 4);
    int* col       = (int*)ws;      ws += align256((size_t)E * 4);
    __half* hs_a   = (__half*)ws;   ws += align256((size_t)n * 64 * 2);
    __half* hs_b   = (__half*)ws;   ws += align256((size_t)n * 64 * 2);
    float* out     = (float*)d_out;

    // ---- CSR build: two-level bucket sort (LDS-binned writes) ----
    k_hist<<<B1, 256, 0, stream>>>(dstp, E, NB, Bh);
    k_bucket_scan<<<NB, 256, 0, stream>>>(Bh, B1, NB, total);
    k_base_scan<<<1, 512, 0, stream>>>(total, NB, E, base);
    k_scatter<<<B1, 256, 0, stream>>>(srcp, dstp, E, NB, Bh, base, ebuf);
    k_bucket_sort<<<NB, 256, 0, stream>>>(ebuf, base, n, E, row_ptr, col);

    int blocks16 = (n + 15) / 16;   // 16 nodes per 256-thread block

    // layer 1 GEMM: hs_a = fp16(dinv * (x @ W1))
    k_gemm_scale<<<blocks16, 256, 0, stream>>>(x, W1, row_ptr, n, hs_a);
    // layer 1 agg (+relu) fused with layer 2 GEMM (MFMA): hs_b
    k_agg_gemm<true><<<blocks16, 256, 0, stream>>>(hs_a, row_ptr, col, b1, W2, n, hs_b);
    // layer 2 agg (no act) fused with layer 3 GEMM (MFMA): hs_a
    k_agg_gemm<false><<<blocks16, 256, 0, stream>>>(hs_b, row_ptr, col, b2, W3, n, hs_a);
    // layer 3 agg + bias + relu -> out
    k_agg_out<<<blocks16, 256, 0, stream>>>(hs_a, row_ptr, col, b3, n, out);
}

// Round 11
// 160.418 us; speedup vs baseline: 2.7874x; 1.0639x over previous
//
#include <hip/hip_runtime.h>
#include <hip/hip_fp16.h>
#include <math.h>

// ---------------------------------------------------------------------------
// GCN 3-layer forward on MI355X.
// Per layer (D=64):
//   hs[i,:] = fp16( dinv[i] * (x[i,:] @ W) )
//   out[i,:]= dinv[i] * (hs[i,:] + sum_{e: dst(e)=i} hs[src(e),:]) + b
//   optional LeakyReLU(0.01);   dinv[i] = rsqrt(1 + indeg(i))
//
// Round-11: build de-barrier-ification.  The CSR build (~40us) was barrier-
// chain bound, not traffic-bound (~7us floor):
//   - all 256-wide LDS ladder scans (16 barriers) -> wave shfl_up scans (2).
//   - k_scatter no longer re-histograms its chunk: k_hist persists raw counts
//     (Bc); scatter loads 391 ints + shfl-scan instead (kills 16 LDS-atomic
//     iterations + ~10 barriers per block).
//   - k_bucket_sort stages the bucket in LDS once (single global read),
//     count/scan/place in LDS, coalesced col writeout.
//   - k_gemm_scale uses the same MFMA phase as agg_gemm (was a 64-iteration
//     LDS-pipe scalar loop).
// Aggs (r8/r10) sit at ~87% of the per-CU streaming byte rate - untouched.
// ---------------------------------------------------------------------------

constexpr int SHIFT = 8;          // bucket = dst >> 8  (256 nodes per bucket)
constexpr int CHUNK = 4096;       // edges per scatter block
constexpr int BCAP  = 5120;       // bucket staging capacity (mean 4096, sd 64)

typedef _Float16 half8 __attribute__((ext_vector_type(8)));
typedef float floatx4 __attribute__((ext_vector_type(4)));

// Exclusive scan of v over 256 threads (2 barriers).  Returns exclusive
// prefix; *total gets the block sum.  wsum = 4-int LDS scratch.
__device__ inline int scan256(int v, int tid, int* wsum, int* total) {
    int lane = tid & 63, w = tid >> 6;
    int inc = v;
#pragma unroll
    for (int off = 1; off < 64; off <<= 1) {
        int t = __shfl_up(inc, off);
        if (lane >= off) inc += t;
    }
    if (lane == 63) wsum[w] = inc;
    __syncthreads();
    int s0 = wsum[0], s1 = wsum[1], s2 = wsum[2], s3 = wsum[3];
    __syncthreads();   // wsum reusable after this
    int base = (w > 0 ? s0 : 0) + (w > 1 ? s1 : 0) + (w > 2 ? s2 : 0);
    *total = s0 + s1 + s2 + s3;
    return base + (inc - v);
}

// ---- phase 1: per-block bucket histogram; Bh (to be scanned) + Bc (raw) ----
__global__ void k_hist(const int* __restrict__ dst, int E, int NB,
                       int* __restrict__ Bh, int* __restrict__ Bc) {
    __shared__ int h[512];
    int tid = threadIdx.x;
    for (int i = tid; i < 512; i += 256) h[i] = 0;
    __syncthreads();
    int s = blockIdx.x * CHUNK;
    int e = min(s + CHUNK, E);
    for (int i = s + tid; i < e; i += 256) atomicAdd(&h[dst[i] >> SHIFT], 1);
    __syncthreads();
    for (int i = tid; i < NB; i += 256) {
        int v = h[i];
        Bh[(size_t)blockIdx.x * NB + i] = v;
        Bc[(size_t)blockIdx.x * NB + i] = v;
    }
}

// ---- phase 1b: per-bucket exclusive scan down the block axis (in place) ----
__global__ void k_bucket_scan(int* __restrict__ Bh, int B1, int NB,
                              int* __restrict__ total) {
    __shared__ int wsum[4];
    int b = blockIdx.x;
    int tid = threadIdx.x;
    int carry = 0;
    for (int j0 = 0; j0 < B1; j0 += 256) {
        int j = j0 + tid;
        int v = (j < B1) ? Bh[(size_t)j * NB + b] : 0;
        int tot;
        int ex = scan256(v, tid, wsum, &tot);
        if (j < B1) Bh[(size_t)j * NB + b] = ex + carry;
        carry += tot;
    }
    if (tid == 0) total[b] = carry;
}

// ---- phase 1c: exclusive scan of bucket totals (NB <= 512), 256 threads ----
__global__ void k_base_scan(const int* __restrict__ total, int NB, int E,
                            int* __restrict__ base) {
    __shared__ int wsum[4];
    int tid = threadIdx.x;
    int b0 = 2 * tid, b1 = 2 * tid + 1;
    int v0 = (b0 < NB) ? total[b0] : 0;
    int v1 = (b1 < NB) ? total[b1] : 0;
    int tot;
    int ex = scan256(v0 + v1, tid, wsum, &tot);
    if (b0 < NB) base[b0] = ex;
    if (b1 < NB) base[b1] = ex + v0;
    if (tid == 0) base[NB] = E;
}

// ---- phase 2: LDS-binned scatter (local offsets from Bc, no re-histogram) --
// record = (dst & 255) << 24 | src      (src < 2^17)
__global__ void k_scatter(const int* __restrict__ src, const int* __restrict__ dst,
                          int E, int NB, const int* __restrict__ Bh,
                          const int* __restrict__ Bc, const int* __restrict__ base,
                          unsigned* __restrict__ ebuf) {
    __shared__ int cur[512];
    __shared__ int gb[512];
    __shared__ int wsum[4];
    __shared__ unsigned srec[CHUNK];
    __shared__ int spos[CHUNK];
    int tid = threadIdx.x;
    int j = blockIdx.x;

    // local exclusive offsets for this block's chunk, from persisted counts
    int b0 = 2 * tid, b1 = 2 * tid + 1;
    int c0 = (b0 < NB) ? Bc[(size_t)j * NB + b0] : 0;
    int c1 = (b1 < NB) ? Bc[(size_t)j * NB + b1] : 0;
    int tot;
    int ex = scan256(c0 + c1, tid, wsum, &tot);
    if (b0 < NB) {
        cur[b0] = ex;
        gb[b0]  = base[b0] + Bh[(size_t)j * NB + b0] - ex;
    }
    if (b1 < NB) {
        int ex1 = ex + c0;
        cur[b1] = ex1;
        gb[b1]  = base[b1] + Bh[(size_t)j * NB + b1] - ex1;
    }
    __syncthreads();

    int s = j * CHUNK;
    int e = min(s + CHUNK, E);
    for (int i = s + tid; i < e; i += 256) {
        int d = dst[i];
        int b = d >> SHIFT;
        unsigned rec = ((unsigned)(d & 255) << 24) | (unsigned)src[i];
        int lpos = atomicAdd(&cur[b], 1);
        srec[lpos] = rec;
        spos[lpos] = gb[b] + lpos;
    }
    __syncthreads();
    int cntE = e - s;
    for (int t = tid; t < cntE; t += 256) ebuf[spos[t]] = srec[t];
}

// ---- phase 3: per-bucket counting sort, LDS-staged -> row_ptr + col --------
__global__ void k_bucket_sort(const unsigned* __restrict__ ebuf,
                              const int* __restrict__ base, int n, int E,
                              int* __restrict__ row_ptr, int* __restrict__ col) {
    __shared__ int cnt[256];
    __shared__ int cur[256];
    __shared__ int wsum[4];
    __shared__ unsigned raw[BCAP];
    __shared__ int sorted[BCAP];
    int b = blockIdx.x;
    int tid = threadIdx.x;
    int s = base[b];
    int e = base[b + 1];
    int len = e - s;
    cnt[tid] = 0;
    __syncthreads();
    if (len <= BCAP) {
        for (int t = tid; t < len; t += 256) {
            unsigned v = ebuf[s + t];   // single global read of the bucket
            raw[t] = v;
            atomicAdd(&cnt[v >> 24], 1);
        }
        __syncthreads();
        int tot;
        int ex = scan256(cnt[tid], tid, wsum, &tot);
        int node = (b << SHIFT) | tid;
        if (node < n) row_ptr[node] = s + ex;
        cur[tid] = ex;
        __syncthreads();
        for (int t = tid; t < len; t += 256) {
            unsigned v = raw[t];
            int lpos = atomicAdd(&cur[v >> 24], 1);
            sorted[lpos] = (int)((v & 0x00FFFFFFu) << 7);   // byte off: src*128
        }
        __syncthreads();
        for (int t = tid; t < len; t += 256) col[s + t] = sorted[t];
    } else {  // statistical-impossibility fallback: two-pass global
        for (int i = s + tid; i < e; i += 256) atomicAdd(&cnt[ebuf[i] >> 24], 1);
        __syncthreads();
        int tot;
        int ex = scan256(cnt[tid], tid, wsum, &tot);
        int node = (b << SHIFT) | tid;
        if (node < n) row_ptr[node] = s + ex;
        cur[tid] = ex;
        __syncthreads();
        for (int i = s + tid; i < e; i += 256) {
            unsigned v = ebuf[i];
            int lpos = atomicAdd(&cur[v >> 24], 1);
            col[s + lpos] = (int)((v & 0x00FFFFFFu) << 7);
        }
    }
    if (b == 0 && tid == 0) row_ptr[n] = E;
}

// ---- shared MFMA tail: rows(16x64 fp16 in LDS) @ WtS -> fp16 HS ------------
__device__ inline void mfma_rows_store(const _Float16* rowS, const _Float16* WtS,
                                       const float* dinvS, int n, int blockRow0,
                                       int tid, __half* __restrict__ HSn) {
    int w = tid >> 6;
    int lane = tid & 63;
    int ar = lane & 15;
    int ks = lane >> 4;

    half8 a1 = *(const half8*)&rowS[ar * 72 + ks * 8];
    half8 a2 = *(const half8*)&rowS[ar * 72 + 32 + ks * 8];
    half8 b1 = *(const half8*)&WtS[(w * 16 + ar) * 72 + ks * 8];
    half8 b2 = *(const half8*)&WtS[(w * 16 + ar) * 72 + 32 + ks * 8];

    floatx4 acc = {0.f, 0.f, 0.f, 0.f};
    acc = __builtin_amdgcn_mfma_f32_16x16x32_f16(a1, b1, acc, 0, 0, 0);
    acc = __builtin_amdgcn_mfma_f32_16x16x32_f16(a2, b2, acc, 0, 0, 0);

    int node0 = (lane >> 4) * 4;
    float4 dv4 = *(const float4*)&dinvS[node0];
    int colg = w * 16 + (lane & 15);
    int base_node = blockRow0 + node0;
#pragma unroll
    for (int reg = 0; reg < 4; reg++) {
        int node_g = base_node + reg;
        if (node_g < n) {
            float dv = (reg == 0) ? dv4.x : (reg == 1) ? dv4.y : (reg == 2) ? dv4.z : dv4.w;
            HSn[(size_t)node_g * 64 + colg] = __float2half(acc[reg] * dv);
        }
    }
}

// stage W^T as fp16 into WtS[64*72]
__device__ inline void stage_wt(const float* __restrict__ Wn, _Float16* WtS, int tid) {
    const float4* W4 = (const float4*)Wn;
#pragma unroll
    for (int j = 0; j < 4; j++) {
        int idx = tid + 256 * j;
        int row = idx >> 4;
        int col0 = (idx & 15) * 4;
        float4 wv = W4[idx];
        WtS[(col0 + 0) * 72 + row] = (_Float16)wv.x;
        WtS[(col0 + 1) * 72 + row] = (_Float16)wv.y;
        WtS[(col0 + 2) * 72 + row] = (_Float16)wv.z;
        WtS[(col0 + 3) * 72 + row] = (_Float16)wv.w;
    }
}

// ---- layer-1 GEMM via MFMA: HS = fp16(dinv * (X @ W)) ----------------------
__global__ void k_gemm_scale(const float* __restrict__ X, const float* __restrict__ W,
                             const int* __restrict__ row_ptr, int n,
                             __half* __restrict__ HS) {
    __shared__ _Float16 WtS[64 * 72];
    __shared__ _Float16 rowS[16 * 72];
    __shared__ float dinvS[16];
    int tid = threadIdx.x;
    stage_wt(W, WtS, tid);

    int g = tid >> 4;
    int c = tid & 15;
    int gid = blockIdx.x * 16 + g;
    if (gid < n) {
        float4 xv = *(const float4*)&X[(size_t)gid * 64 + c * 4];
        __half2 h0 = __floats2half2_rn(xv.x, xv.y);
        __half2 h1 = __floats2half2_rn(xv.z, xv.w);
        uint2 pack;
        pack.x = *(const unsigned int*)&h0;
        pack.y = *(const unsigned int*)&h1;
        *(uint2*)&rowS[g * 72 + c * 4] = pack;
        if (c == 0)
            dinvS[g] = rsqrtf(1.0f + (float)(row_ptr[gid + 1] - row_ptr[gid]));
    }
    __syncthreads();
    mfma_rows_store(rowS, WtS, dinvS, n, blockIdx.x * 16, tid, HS);
}

__device__ inline float4 cvt_h4(uint2 v) {
    float2 f0 = __half22float2(*(__half2*)&v.x);
    float2 f1 = __half22float2(*(__half2*)&v.y);
    return make_float4(f0.x, f0.y, f1.x, f1.y);
}

__device__ inline uint2 ld_row(const char* HSb, int boff, int c) {
    return *(const uint2*)(HSb + boff + (c << 3));
}

// Gather-aggregate one node's row: s = hs[self] + sum hs[src].  16-lane
// group, 8 gathers in flight (main), 4-batch, predicated singles.
__device__ inline float4 agg_row(const char* __restrict__ HSb,
                                 const int* __restrict__ col,
                                 int gid, int c, int r0, int r1) {
    float4 a0 = cvt_h4(*(const uint2*)(HSb + ((size_t)gid << 7) + (c << 3)));
    float4 a1 = make_float4(0.f, 0.f, 0.f, 0.f);
    float4 a2 = a1, a3 = a1;
    int e = r0;
    for (; e + 8 <= r1; e += 8) {
        int s0 = col[e + 0], s1 = col[e + 1], s2 = col[e + 2], s3 = col[e + 3];
        int s4 = col[e + 4], s5 = col[e + 5], s6 = col[e + 6], s7 = col[e + 7];
        uint2 v0 = ld_row(HSb, s0, c), v1 = ld_row(HSb, s1, c);
        uint2 v2 = ld_row(HSb, s2, c), v3 = ld_row(HSb, s3, c);
        uint2 v4 = ld_row(HSb, s4, c), v5 = ld_row(HSb, s5, c);
        uint2 v6 = ld_row(HSb, s6, c), v7 = ld_row(HSb, s7, c);
        float4 f0 = cvt_h4(v0), f1 = cvt_h4(v1), f2 = cvt_h4(v2), f3 = cvt_h4(v3);
        float4 f4 = cvt_h4(v4), f5 = cvt_h4(v5), f6 = cvt_h4(v6), f7 = cvt_h4(v7);
        a0.x += f0.x; a0.y += f0.y; a0.z += f0.z; a0.w += f0.w;
        a1.x += f1.x; a1.y += f1.y; a1.z += f1.z; a1.w += f1.w;
        a2.x += f2.x; a2.y += f2.y; a2.z += f2.z; a2.w += f2.w;
        a3.x += f3.x; a3.y += f3.y; a3.z += f3.z; a3.w += f3.w;
        a0.x += f4.x; a0.y += f4.y; a0.z += f4.z; a0.w += f4.w;
        a1.x += f5.x; a1.y += f5.y; a1.z += f5.z; a1.w += f5.w;
        a2.x += f6.x; a2.y += f6.y; a2.z += f6.z; a2.w += f6.w;
        a3.x += f7.x; a3.y += f7.y; a3.z += f7.z; a3.w += f7.w;
    }
    if (e + 4 <= r1) {
        int s0 = col[e + 0], s1 = col[e + 1], s2 = col[e + 2], s3 = col[e + 3];
        uint2 v0 = ld_row(HSb, s0, c), v1 = ld_row(HSb, s1, c);
        uint2 v2 = ld_row(HSb, s2, c), v3 = ld_row(HSb, s3, c);
        float4 f0 = cvt_h4(v0), f1 = cvt_h4(v1), f2 = cvt_h4(v2), f3 = cvt_h4(v3);
        a0.x += f0.x; a0.y += f0.y; a0.z += f0.z; a0.w += f0.w;
        a1.x += f1.x; a1.y += f1.y; a1.z += f1.z; a1.w += f1.w;
        a2.x += f2.x; a2.y += f2.y; a2.z += f2.z; a2.w += f2.w;
        a3.x += f3.x; a3.y += f3.y; a3.z += f3.z; a3.w += f3.w;
        e += 4;
    }
    if (e + 0 < r1) {
        float4 f = cvt_h4(ld_row(HSb, col[e + 0], c));
        a0.x += f.x; a0.y += f.y; a0.z += f.z; a0.w += f.w;
    }
    if (e + 1 < r1) {
        float4 f = cvt_h4(ld_row(HSb, col[e + 1], c));
        a1.x += f.x; a1.y += f.y; a1.z += f.z; a1.w += f.w;
    }
    if (e + 2 < r1) {
        float4 f = cvt_h4(ld_row(HSb, col[e + 2], c));
        a2.x += f.x; a2.y += f.y; a2.z += f.z; a2.w += f.w;
    }
    float4 s;
    s.x = (a0.x + a1.x) + (a2.x + a3.x);
    s.y = (a0.y + a1.y) + (a2.y + a3.y);
    s.z = (a0.z + a1.z) + (a2.z + a3.z);
    s.w = (a0.w + a1.w) + (a2.w + a3.w);
    return s;
}

// ---- fused: agg epilogue + next-layer GEMM (MFMA) -> fp16 hs_next ---------
template <bool RELU>
__global__ void k_agg_gemm(const __half* __restrict__ HS, const int* __restrict__ row_ptr,
                           const int* __restrict__ col, const float* __restrict__ bias,
                           const float* __restrict__ Wn, int n,
                           __half* __restrict__ HSn) {
    __shared__ _Float16 WtS[64 * 72];
    __shared__ _Float16 rowS[16 * 72];
    __shared__ float dinvS[16];
    int tid = threadIdx.x;
    stage_wt(Wn, WtS, tid);

    int g = tid >> 4;
    int c = tid & 15;
    int gid = blockIdx.x * 16 + g;

    if (gid < n) {
        const char* __restrict__ HSb = (const char*)HS;
        int r0 = row_ptr[gid];
        int r1 = row_ptr[gid + 1];
        float4 s = agg_row(HSb, col, gid, c, r0, r1);
        float deg = 1.0f + (float)(r1 - r0);
        float dinv = rsqrtf(deg);
        float4 bv = *(const float4*)&bias[4 * c];
        float vx = dinv * s.x + bv.x;
        float vy = dinv * s.y + bv.y;
        float vz = dinv * s.z + bv.z;
        float vw = dinv * s.w + bv.w;
        if (RELU) {
            vx = (vx >= 0.f) ? vx : 0.01f * vx;
            vy = (vy >= 0.f) ? vy : 0.01f * vy;
            vz = (vz >= 0.f) ? vz : 0.01f * vz;
            vw = (vw >= 0.f) ? vw : 0.01f * vw;
        }
        __half2 h0 = __floats2half2_rn(vx, vy);
        __half2 h1 = __floats2half2_rn(vz, vw);
        uint2 pack;
        pack.x = *(const unsigned int*)&h0;
        pack.y = *(const unsigned int*)&h1;
        *(uint2*)&rowS[g * 72 + c * 4] = pack;
        if (c == 0) dinvS[g] = dinv;
    }
    __syncthreads();
    mfma_rows_store(rowS, WtS, dinvS, n, blockIdx.x * 16, tid, HSn);
}

// ---- final layer: agg + bias + LeakyReLU -> fp32 out ----------------------
__global__ void k_agg_out(const __half* __restrict__ HS, const int* __restrict__ row_ptr,
                          const int* __restrict__ col, const float* __restrict__ bias,
                          int n, float* __restrict__ out) {
    int gid = (int)((blockIdx.x * (unsigned)blockDim.x + threadIdx.x) >> 4);
    if (gid >= n) return;
    int c = threadIdx.x & 15;
    const char* __restrict__ HSb = (const char*)HS;
    int r0 = row_ptr[gid];
    int r1 = row_ptr[gid + 1];
    float4 s = agg_row(HSb, col, gid, c, r0, r1);
    float deg = 1.0f + (float)(r1 - r0);
    float dinv = rsqrtf(deg);
    float4 bv = *(const float4*)&bias[4 * c];
    float vx = dinv * s.x + bv.x;
    float vy = dinv * s.y + bv.y;
    float vz = dinv * s.z + bv.z;
    float vw = dinv * s.w + bv.w;
    vx = (vx >= 0.f) ? vx : 0.01f * vx;
    vy = (vy >= 0.f) ? vy : 0.01f * vy;
    vz = (vz >= 0.f) ? vz : 0.01f * vz;
    vw = (vw >= 0.f) ? vw : 0.01f * vw;
    *(float4*)&out[(size_t)gid * 64 + 4 * c] = make_float4(vx, vy, vz, vw);
}

static inline size_t align256(size_t x) { return (x + 255) & ~(size_t)255; }

extern "C" void kernel_launch(void* const* d_in, const int* in_sizes, int n_in,
                              void* d_out, int out_size, void* d_ws, size_t ws_size,
                              hipStream_t stream) {
    const float* x  = (const float*)d_in[0];
    const float* W1 = (const float*)d_in[1];
    const float* b1 = (const float*)d_in[2];
    const float* W2 = (const float*)d_in[3];
    const float* b2 = (const float*)d_in[4];
    const float* W3 = (const float*)d_in[5];
    const float* b3 = (const float*)d_in[6];
    const int* edge = (const int*)d_in[7];

    int n = in_sizes[0] / 64;
    int E = in_sizes[7] / 2;
    const int* srcp = edge;
    const int* dstp = edge + E;

    int NB = (n + 255) >> SHIFT;              // buckets (391 for n=100000)
    int B1 = (E + CHUNK - 1) / CHUNK;         // histogram/scatter blocks

    char* ws = (char*)d_ws;
    int* row_ptr   = (int*)ws;      ws += align256((size_t)(n + 1) * 4);
    int* Bh        = (int*)ws;      ws += align256((size_t)B1 * NB * 4);
    int* Bc        = (int*)ws;      ws += align256((size_t)B1 * NB * 4);
    int* total     = (int*)ws;      ws += align256((size_t)NB * 4);
    int* base      = (int*)ws;      ws += align256((size_t)(NB + 1) * 4);
    unsigned* ebuf = (unsigned*)ws; ws += align256((size_t)E * 4);
    int* col       = (int*)ws;      ws += align256((size_t)E * 4);
    __half* hs_a   = (__half*)ws;   ws += align256((size_t)n * 64 * 2);
    __half* hs_b   = (__half*)ws;   ws += align256((size_t)n * 64 * 2);
    float* out     = (float*)d_out;

    // ---- CSR build: two-level bucket sort (shfl scans, LDS-binned writes) --
    k_hist<<<B1, 256, 0, stream>>>(dstp, E, NB, Bh, Bc);
    k_bucket_scan<<<NB, 256, 0, stream>>>(Bh, B1, NB, total);
    k_base_scan<<<1, 256, 0, stream>>>(total, NB, E, base);
    k_scatter<<<B1, 256, 0, stream>>>(srcp, dstp, E, NB, Bh, Bc, base, ebuf);
    k_bucket_sort<<<NB, 256, 0, stream>>>(ebuf, base, n, E, row_ptr, col);

    int blocks16 = (n + 15) / 16;   // 16 nodes per 256-thread block

    // layer 1 GEMM (MFMA): hs_a = fp16(dinv * (x @ W1))
    k_gemm_scale<<<blocks16, 256, 0, stream>>>(x, W1, row_ptr, n, hs_a);
    // layer 1 agg (+relu) fused with layer 2 GEMM (MFMA): hs_b
    k_agg_gemm<true><<<blocks16, 256, 0, stream>>>(hs_a, row_ptr, col, b1, W2, n, hs_b);
    // layer 2 agg (no act) fused with layer 3 GEMM (MFMA): hs_a
    k_agg_gemm<false><<<blocks16, 256, 0, stream>>>(hs_b, row_ptr, col, b2, W3, n, hs_a);
    // layer 3 agg + bias + relu -> out
    k_agg_out<<<blocks16, 256, 0, stream>>>(hs_a, row_ptr, col, b3, n, out);
}